// Round 1
// baseline (209.494 us; speedup 1.0000x reference)
//
#include <hip/hip_runtime.h>
#include <math.h>

#define BB  64
#define WW  128
#define NN  64
#define BN  4096
#define HIDN 77

// ---------------- K0: CSR build (single block) ----------------
// Edge structure is identical across batches (offset by b*N), so build
// per-node (dst) CSR from batch 0's slice, including self-loops, plus
// GCN deg/dinv coefficients per edge.
__global__ __launch_bounds__(256) void k_csr(const int* __restrict__ gl_ei, int E_gl,
                                             const int* __restrict__ gat_ei, int E_gat,
                                             int* __restrict__ gl_off, int* __restrict__ gl_list,
                                             float* __restrict__ gl_coef,
                                             int* __restrict__ gat_off, int* __restrict__ gat_list) {
  __shared__ int cnt[64], offs[65], cur[64];
  __shared__ int lst[2048];
  __shared__ float dv[64];
  int tid = threadIdx.x;

  // ---- GL (GCN) edges ----
  if (tid < 64) cnt[tid] = 1;  // self loop
  __syncthreads();
  for (int e = tid; e < E_gl; e += 256) atomicAdd(&cnt[gl_ei[BB * E_gl + e]], 1);
  __syncthreads();
  if (tid == 0) { int s = 0; for (int n = 0; n < 64; n++) { offs[n] = s; s += cnt[n]; } offs[64] = s; }
  __syncthreads();
  if (tid < 64) { cur[tid] = offs[tid]; dv[tid] = rsqrtf((float)cnt[tid]); }
  __syncthreads();
  for (int e = tid; e < E_gl; e += 256) {
    int src = gl_ei[e];
    int dst = gl_ei[BB * E_gl + e];
    int pos = atomicAdd(&cur[dst], 1);
    lst[pos] = src;
  }
  if (tid < 64) { int pos = atomicAdd(&cur[tid], 1); lst[pos] = tid; }
  __syncthreads();
  int totG = offs[64];
  if (tid < 65) gl_off[tid] = offs[tid];
  for (int i = tid; i < totG; i += 256) gl_list[i] = lst[i];
  if (tid < 64) {
    float dn = dv[tid];
    for (int e = offs[tid]; e < offs[tid + 1]; e++) gl_coef[e] = dv[lst[e]] * dn;
  }
  __syncthreads();

  // ---- GAT edges ----
  if (tid < 64) cnt[tid] = 1;
  __syncthreads();
  for (int e = tid; e < E_gat; e += 256) atomicAdd(&cnt[gat_ei[BB * E_gat + e]], 1);
  __syncthreads();
  if (tid == 0) { int s = 0; for (int n = 0; n < 64; n++) { offs[n] = s; s += cnt[n]; } offs[64] = s; }
  __syncthreads();
  if (tid < 64) cur[tid] = offs[tid];
  __syncthreads();
  for (int e = tid; e < E_gat; e += 256) {
    int src = gat_ei[e];
    int dst = gat_ei[BB * E_gat + e];
    int pos = atomicAdd(&cur[dst], 1);
    lst[pos] = src;
  }
  if (tid < 64) { int pos = atomicAdd(&cur[tid], 1); lst[pos] = tid; }
  __syncthreads();
  int totA = offs[64];
  if (tid < 65) gat_off[tid] = offs[tid];
  for (int i = tid; i < totA; i += 256) gat_list[i] = lst[i];
}

// ---------------- K1: x (B,W,N) -> x_batch (B*N, W) ----------------
__global__ __launch_bounds__(256) void k_xbatch(const float* __restrict__ x, float* __restrict__ xb) {
  __shared__ float t[64 * 129];
  int b = blockIdx.x;
  const float* xp = x + (size_t)b * 8192;
  for (int idx = threadIdx.x; idx < 8192; idx += 256) {
    int w = idx >> 6, n = idx & 63;
    t[n * 129 + w] = xp[idx];
  }
  __syncthreads();
  float* o = xb + (size_t)b * 8192;
  for (int idx = threadIdx.x; idx < 8192; idx += 256) {
    int n = idx >> 7, w = idx & 127;
    o[idx] = t[n * 129 + w];
  }
}

// ---------------- K2: hraw = [x_batch | gl_embed] @ gcn_w  (4096x140 @ 140x128) ----------------
__global__ __launch_bounds__(256) void k_gcn_gemm(const float* __restrict__ xb, const float* __restrict__ emb,
                                                  const float* __restrict__ wg, float* __restrict__ hraw) {
  int wave = threadIdx.x >> 6, lane = threadIdx.x & 63;
  int r0 = (blockIdx.x * 4 + wave) * 4;
  int c = lane * 2;
  float ax[4] = {0, 0, 0, 0}, ay[4] = {0, 0, 0, 0};
  for (int k = 0; k < 128; k += 4) {
    float2 w0 = *(const float2*)&wg[(k + 0) * 128 + c];
    float2 w1 = *(const float2*)&wg[(k + 1) * 128 + c];
    float2 w2 = *(const float2*)&wg[(k + 2) * 128 + c];
    float2 w3 = *(const float2*)&wg[(k + 3) * 128 + c];
#pragma unroll
    for (int rr = 0; rr < 4; rr++) {
      float4 a = *(const float4*)&xb[(size_t)(r0 + rr) * 128 + k];
      ax[rr] += a.x * w0.x + a.y * w1.x + a.z * w2.x + a.w * w3.x;
      ay[rr] += a.x * w0.y + a.y * w1.y + a.z * w2.y + a.w * w3.y;
    }
  }
  int n0 = r0 & 63;
  for (int k = 0; k < 12; k++) {
    float2 wv = *(const float2*)&wg[(128 + k) * 128 + c];
#pragma unroll
    for (int rr = 0; rr < 4; rr++) {
      float a = emb[(n0 + rr) * 12 + k];
      ax[rr] += a * wv.x; ay[rr] += a * wv.y;
    }
  }
#pragma unroll
  for (int rr = 0; rr < 4; rr++) {
    float2 o; o.x = ax[rr]; o.y = ay[rr];
    *(float2*)&hraw[(size_t)(r0 + rr) * 128 + c] = o;
  }
}

// ---------------- K3: GCN aggregate + bias + relu (wave per (b,n)) ----------------
__global__ __launch_bounds__(256) void k_gcn_agg(const float* __restrict__ hraw, const int* __restrict__ off,
                                                 const int* __restrict__ list, const float* __restrict__ coef,
                                                 const float* __restrict__ bias, float* __restrict__ hA) {
  int wave = threadIdx.x >> 6, lane = threadIdx.x & 63;
  int r = blockIdx.x * 4 + wave;
  int b = r >> 6, n = r & 63, c = lane * 2;
  int e0 = off[n], e1 = off[n + 1];
  const float* base = hraw + (size_t)b * 8192;
  float accx = 0.f, accy = 0.f;
  for (int e = e0; e < e1; e++) {
    int s = list[e];
    float cf = coef[e];
    float2 h = *(const float2*)&base[s * 128 + c];
    accx += cf * h.x; accy += cf * h.y;
  }
  accx = fmaxf(accx + bias[c], 0.f);
  accy = fmaxf(accy + bias[c + 1], 0.f);
  float2 o; o.x = accx; o.y = accy;
  *(float2*)&hA[(size_t)r * 128 + c] = o;
}

// ---------------- K4: hmid = tanh(hA @ mlp_w1 + b1)  (4096x128 @ 128x77, stride-80 out) ----------------
__global__ __launch_bounds__(256) void k_mlp1(const float* __restrict__ hA, const float* __restrict__ w1,
                                              const float* __restrict__ b1, float* __restrict__ hmid) {
  int wave = threadIdx.x >> 6, lane = threadIdx.x & 63;
  int r0 = (blockIdx.x * 4 + wave) * 4;
  int c0 = lane, c1 = lane + 64;
  bool v1 = (c1 < HIDN);
  float a0[4] = {0, 0, 0, 0}, a1[4] = {0, 0, 0, 0};
  for (int k = 0; k < 128; k += 4) {
    float w00 = w1[(k + 0) * HIDN + c0], w01 = w1[(k + 1) * HIDN + c0];
    float w02 = w1[(k + 2) * HIDN + c0], w03 = w1[(k + 3) * HIDN + c0];
    float w10 = v1 ? w1[(k + 0) * HIDN + c1] : 0.f;
    float w11 = v1 ? w1[(k + 1) * HIDN + c1] : 0.f;
    float w12 = v1 ? w1[(k + 2) * HIDN + c1] : 0.f;
    float w13 = v1 ? w1[(k + 3) * HIDN + c1] : 0.f;
#pragma unroll
    for (int rr = 0; rr < 4; rr++) {
      float4 a = *(const float4*)&hA[(size_t)(r0 + rr) * 128 + k];
      a0[rr] += a.x * w00 + a.y * w01 + a.z * w02 + a.w * w03;
      a1[rr] += a.x * w10 + a.y * w11 + a.z * w12 + a.w * w13;
    }
  }
  float bb0 = b1[c0], bb1 = v1 ? b1[c1] : 0.f;
#pragma unroll
  for (int rr = 0; rr < 4; rr++) {
    hmid[(size_t)(r0 + rr) * 80 + c0] = tanhf(a0[rr] + bb0);
    if (v1) hmid[(size_t)(r0 + rr) * 80 + c1] = tanhf(a1[rr] + bb1);
  }
}

// ---------------- K5: x_rec = tanh(hmid @ mlp_w2 + b2); xs = x_batch + x_rec ----------------
__global__ __launch_bounds__(256) void k_mlp2(const float* __restrict__ hmid, const float* __restrict__ w2,
                                              const float* __restrict__ b2, const float* __restrict__ xb,
                                              float* __restrict__ xrec, float* __restrict__ xs) {
  int wave = threadIdx.x >> 6, lane = threadIdx.x & 63;
  int r0 = (blockIdx.x * 4 + wave) * 4;
  int c = lane * 2;
  float ax[4] = {0, 0, 0, 0}, ay[4] = {0, 0, 0, 0};
  for (int k = 0; k < 76; k += 4) {
    float2 w0 = *(const float2*)&w2[(k + 0) * 128 + c];
    float2 w1v = *(const float2*)&w2[(k + 1) * 128 + c];
    float2 w2v = *(const float2*)&w2[(k + 2) * 128 + c];
    float2 w3v = *(const float2*)&w2[(k + 3) * 128 + c];
#pragma unroll
    for (int rr = 0; rr < 4; rr++) {
      float4 a = *(const float4*)&hmid[(size_t)(r0 + rr) * 80 + k];
      ax[rr] += a.x * w0.x + a.y * w1v.x + a.z * w2v.x + a.w * w3v.x;
      ay[rr] += a.x * w0.y + a.y * w1v.y + a.z * w2v.y + a.w * w3v.y;
    }
  }
  {
    float2 wv = *(const float2*)&w2[76 * 128 + c];
#pragma unroll
    for (int rr = 0; rr < 4; rr++) {
      float a = hmid[(size_t)(r0 + rr) * 80 + 76];
      ax[rr] += a * wv.x; ay[rr] += a * wv.y;
    }
  }
  float2 bv = *(const float2*)&b2[c];
#pragma unroll
  for (int rr = 0; rr < 4; rr++) {
    float rx = tanhf(ax[rr] + bv.x), ry = tanhf(ay[rr] + bv.y);
    float2 o; o.x = rx; o.y = ry;
    *(float2*)&xrec[(size_t)(r0 + rr) * 128 + c] = o;
    float2 xv = *(const float2*)&xb[(size_t)(r0 + rr) * 128 + c];
    float2 s; s.x = xv.x + rx; s.y = xv.y + ry;
    *(float2*)&xs[(size_t)(r0 + rr) * 128 + c] = s;
  }
}

// ---------------- K5b: out_rec[b,w,n] = x_rec[b*N+n, w] ----------------
__global__ __launch_bounds__(256) void k_rec_t(const float* __restrict__ xrec, float* __restrict__ out) {
  __shared__ float t[128 * 65];
  int b = blockIdx.x;
  const float* p = xrec + (size_t)b * 8192;
  for (int idx = threadIdx.x; idx < 8192; idx += 256) {
    int n = idx >> 7, w = idx & 127;
    t[w * 65 + n] = p[idx];
  }
  __syncthreads();
  float* o = out + (size_t)b * 8192;
  for (int idx = threadIdx.x; idx < 8192; idx += 256) {
    int w = idx >> 6, n = idx & 63;
    o[idx] = t[w * 65 + n];
  }
}

// ---------------- K6: leftT[b][e][i] = sum_n xs[b,n,i]*ta_w[n,e] (+ta_b fold); rightT similarly ----------------
__global__ __launch_bounds__(256) void k_lr(const float* __restrict__ xs, const float* __restrict__ ta_w,
                                            const float* __restrict__ ta_b, float* __restrict__ leftT,
                                            float* __restrict__ rightT) {
  int wave = threadIdx.x >> 6, lane = threadIdx.x & 63;
  int idx = blockIdx.x * 4 + wave;
  int b = idx >> 7, e = idx & 127;
  int c = lane * 2;
  const float* xsb = xs + (size_t)b * 8192;
  float lx = 0, ly = 0, rx = 0, ry = 0;
  for (int n = 0; n < 64; n++) {
    float wl = ta_w[n * 128 + e];
    float wr = ta_w[(64 + n) * 128 + e];
    float2 xv = *(const float2*)&xsb[n * 128 + c];
    lx += wl * xv.x; ly += wl * xv.y;
    rx += wr * xv.x; ry += wr * xv.y;
  }
  float tb = ta_b[e];
  float2 lo; lo.x = lx + tb; lo.y = ly + tb;
  float2 ro; ro.x = rx; ro.y = ry;
  *(float2*)&leftT[((size_t)b * 128 + e) * 128 + c] = lo;
  *(float2*)&rightT[((size_t)b * 128 + e) * 128 + c] = ro;
}

// ---------------- K7: e-scores: G[b,i,j] = sum_e leaky(L+R)*a + ta_bias ----------------
__global__ __launch_bounds__(512) void k_escore(const float* __restrict__ leftT, const float* __restrict__ rightT,
                                                const float* __restrict__ ta_a, const float* __restrict__ ta_bias,
                                                float* __restrict__ G) {
  __shared__ float Lh[128 * 64];
  __shared__ float Rf[128 * 128];
  __shared__ float av[128];
  int tid = threadIdx.x;
  int b = blockIdx.x >> 1, ih = blockIdx.x & 1;
  for (int idx = tid; idx < 128 * 64; idx += 512) {
    int e = idx >> 6, ii = idx & 63;
    Lh[idx] = leftT[((size_t)b * 128 + e) * 128 + ih * 64 + ii];
  }
  for (int idx = tid; idx < 128 * 128; idx += 512) {
    Rf[idx] = rightT[(size_t)b * 16384 + idx];
  }
  if (tid < 128) av[tid] = ta_a[tid];
  __syncthreads();
  int ti = tid >> 5, tj = tid & 31;
  int i0 = ti * 4, j0 = tj * 4;
  float acc[4][4];
#pragma unroll
  for (int a = 0; a < 4; a++)
#pragma unroll
    for (int q = 0; q < 4; q++) acc[a][q] = 0.f;
  for (int e = 0; e < 128; e++) {
    float4 Lv = *(const float4*)&Lh[e * 64 + i0];
    float4 Rv = *(const float4*)&Rf[e * 128 + j0];
    float ae = av[e];
    float La[4] = {Lv.x, Lv.y, Lv.z, Lv.w};
    float Ra[4] = {Rv.x, Rv.y, Rv.z, Rv.w};
#pragma unroll
    for (int a = 0; a < 4; a++)
#pragma unroll
      for (int q = 0; q < 4; q++) {
        float t = La[a] + Ra[q];
        float l = fmaxf(t, 0.2f * t);
        acc[a][q] += l * ae;
      }
  }
#pragma unroll
  for (int a = 0; a < 4; a++) {
    int i = ih * 64 + i0 + a;
    float4 bv = *(const float4*)&ta_bias[(size_t)i * 128 + j0];
    float4 o;
    o.x = acc[a][0] + bv.x; o.y = acc[a][1] + bv.y;
    o.z = acc[a][2] + bv.z; o.w = acc[a][3] + bv.w;
    *(float4*)&G[((size_t)b * 128 + i) * 128 + j0] = o;
  }
}

// ---------------- K8: softmax over j + PV + tanh -> ht (B,W,N) ----------------
__global__ __launch_bounds__(256) void k_softpv(const float* __restrict__ G, const float* __restrict__ xs,
                                                float* __restrict__ ht) {
  __shared__ float xsT[128 * 65];
  __shared__ float pl[32 * 128];
  int tid = threadIdx.x;
  int b = blockIdx.x >> 2, iq = blockIdx.x & 3;
  const float* xsb = xs + (size_t)b * 8192;
  for (int idx = tid; idx < 8192; idx += 256) {
    int n = idx >> 7, j = idx & 127;
    xsT[j * 65 + n] = xsb[idx];
  }
  __syncthreads();
  int wave = tid >> 6, lane = tid & 63;
  int ibase = iq * 32 + wave * 8;
#pragma unroll
  for (int s = 0; s < 8; s++) {
    int i = ibase + s;
    float2 ev = *(const float2*)&G[((size_t)b * 128 + i) * 128 + lane * 2];
    float m = fmaxf(ev.x, ev.y);
#pragma unroll
    for (int o = 32; o > 0; o >>= 1) m = fmaxf(m, __shfl_xor(m, o));
    float p0 = __expf(ev.x - m), p1 = __expf(ev.y - m);
    float sm = p0 + p1;
#pragma unroll
    for (int o = 32; o > 0; o >>= 1) sm += __shfl_xor(sm, o);
    float inv = 1.f / sm;
    pl[(wave * 8 + s) * 128 + lane * 2] = p0 * inv;
    pl[(wave * 8 + s) * 128 + lane * 2 + 1] = p1 * inv;
  }
  __syncthreads();
  float acc[8] = {0, 0, 0, 0, 0, 0, 0, 0};
  for (int j = 0; j < 128; j++) {
    float xv = xsT[j * 65 + lane];
#pragma unroll
    for (int s = 0; s < 8; s++) acc[s] += pl[(wave * 8 + s) * 128 + j] * xv;
  }
#pragma unroll
  for (int s = 0; s < 8; s++) {
    ht[((size_t)b * 128 + ibase + s) * 64 + lane] = tanhf(acc[s]);
  }
}

// ---------------- K9: h2 = hg @ gat_w (hg read as ht^T); s_src/s_dst epilogue ----------------
__global__ __launch_bounds__(256) void k_gatgemm(const float* __restrict__ ht, const float* __restrict__ gw,
                                                 const float* __restrict__ asrc, const float* __restrict__ adst,
                                                 float* __restrict__ h2, float* __restrict__ ssrc,
                                                 float* __restrict__ sdst) {
  int wave = threadIdx.x >> 6, lane = threadIdx.x & 63;
  int r0 = (blockIdx.x * 4 + wave) * 4;
  int b = r0 >> 6, n0 = r0 & 63;
  int c = lane * 2;
  float ax[4] = {0, 0, 0, 0}, ay[4] = {0, 0, 0, 0};
  for (int k = 0; k < 128; k++) {
    float2 wv = *(const float2*)&gw[k * 128 + c];
    float4 a = *(const float4*)&ht[((size_t)b * 128 + k) * 64 + n0];
    float aa[4] = {a.x, a.y, a.z, a.w};
#pragma unroll
    for (int rr = 0; rr < 4; rr++) { ax[rr] += aa[rr] * wv.x; ay[rr] += aa[rr] * wv.y; }
  }
  float as0 = asrc[c], as1 = asrc[c + 1], ad0 = adst[c], ad1 = adst[c + 1];
#pragma unroll
  for (int rr = 0; rr < 4; rr++) {
    float2 o; o.x = ax[rr]; o.y = ay[rr];
    *(float2*)&h2[(size_t)(r0 + rr) * 128 + c] = o;
    float ss = ax[rr] * as0 + ay[rr] * as1;
    float sd = ax[rr] * ad0 + ay[rr] * ad1;
#pragma unroll
    for (int o2 = 32; o2 > 0; o2 >>= 1) { ss += __shfl_xor(ss, o2); sd += __shfl_xor(sd, o2); }
    if (lane == 0) { ssrc[r0 + rr] = ss; sdst[r0 + rr] = sd; }
  }
}

// ---------------- K10: GAT edge-softmax aggregate + bias + fused FC + tanh -> x_pre ----------------
__global__ __launch_bounds__(256) void k_gatagg(const float* __restrict__ h2, const float* __restrict__ ssrc,
                                                const float* __restrict__ sdst, const int* __restrict__ off,
                                                const int* __restrict__ list, const float* __restrict__ gb,
                                                const float* __restrict__ fcw, const float* __restrict__ fcb,
                                                float* __restrict__ outp) {
  int wave = threadIdx.x >> 6, lane = threadIdx.x & 63;
  int r = blockIdx.x * 4 + wave;
  int b = r >> 6, n = r & 63, c = lane * 2;
  int e0 = off[n], e1 = off[n + 1];
  const float* sb = ssrc + b * 64;
  float sd = sdst[r];
  float m = -1e30f;
  for (int e = e0; e < e1; e++) {
    float ev = sb[list[e]] + sd;
    ev = fmaxf(ev, 0.2f * ev);
    m = fmaxf(m, ev);
  }
  const float* hb = h2 + (size_t)b * 8192;
  float den = 0.f, accx = 0.f, accy = 0.f;
  for (int e = e0; e < e1; e++) {
    int s = list[e];
    float ev = sb[s] + sd;
    ev = fmaxf(ev, 0.2f * ev);
    float w = __expf(ev - m);
    den += w;
    float2 h = *(const float2*)&hb[s * 128 + c];
    accx += w * h.x; accy += w * h.y;
  }
  float inv = 1.f / den;
  float o0 = accx * inv + gb[c], o1 = accy * inv + gb[c + 1];
  float xp = o0 * fcw[c] + o1 * fcw[c + 1];
#pragma unroll
  for (int o2 = 32; o2 > 0; o2 >>= 1) xp += __shfl_xor(xp, o2);
  if (lane == 0) outp[r] = tanhf(xp + fcb[0]);
}

extern "C" void kernel_launch(void* const* d_in, const int* in_sizes, int n_in,
                              void* d_out, int out_size, void* d_ws, size_t ws_size,
                              hipStream_t stream) {
  (void)n_in; (void)out_size; (void)ws_size;
  const float* x        = (const float*)d_in[0];
  const float* gl_embed = (const float*)d_in[7];
  const float* gcn_w    = (const float*)d_in[8];
  const float* gcn_b    = (const float*)d_in[9];
  const float* mlp_w1   = (const float*)d_in[10];
  const float* mlp_b1   = (const float*)d_in[11];
  const float* mlp_w2   = (const float*)d_in[12];
  const float* mlp_b2   = (const float*)d_in[13];
  const float* ta_w     = (const float*)d_in[14];
  const float* ta_b     = (const float*)d_in[15];
  const float* ta_a     = (const float*)d_in[16];
  const float* ta_bias  = (const float*)d_in[17];
  const float* gat_w    = (const float*)d_in[18];
  const float* gat_asrc = (const float*)d_in[19];
  const float* gat_adst = (const float*)d_in[20];
  const float* gat_b    = (const float*)d_in[21];
  const float* fc_w     = (const float*)d_in[22];
  const float* fc_b     = (const float*)d_in[23];
  const int*   gat_ei   = (const int*)d_in[24];
  const int*   gl_ei    = (const int*)d_in[25];

  int E_gat = in_sizes[24] / (2 * BB);  // 1280
  int E_gl  = in_sizes[25] / (2 * BB);  // 1638

  float* ws = (float*)d_ws;
  // float-region offsets (elements); LEFT/RIGHT/HT alias dead earlier buffers
  float* XB    = ws + 0;        // 524288  (later reused as HT)
  float* HRAW  = ws + 524288;   // 524288
  float* HA    = ws + 1048576;  // 524288
  float* HMID  = ws + 1572864;  // 327680 (4096 x 80)
  float* XREC  = ws + 1900544;  // 524288
  float* XS    = ws + 2621440;  // 524288
  float* LEFT  = ws + 524288;   // 1048576 (aliases HRAW+HA, dead by K6)
  float* RIGHT = ws + 1572864;  // 1048576 (aliases HMID+XREC, dead by K6)
  float* G     = ws + 3145728;  // 1048576
  float* HT    = ws + 0;        // 524288 (aliases XB, dead by K8)
  float* H2    = ws + 4194304;  // 524288
  float* SSRC  = ws + 4718592;  // 4096
  float* SDST  = ws + 4722688;  // 4096
  float* COEF  = ws + 4726784;  // 2048
  int*   IP    = (int*)(ws + 4728832);
  int* GLOFF   = IP;            // 72
  int* GLLIST  = IP + 72;       // 2048
  int* GATOFF  = IP + 2120;     // 72
  int* GATLIST = IP + 2192;     // 2048

  float* out_rec = (float*)d_out;
  float* out_pre = (float*)d_out + 524288;

  k_csr<<<1, 256, 0, stream>>>(gl_ei, E_gl, gat_ei, E_gat, GLOFF, GLLIST, COEF, GATOFF, GATLIST);
  k_xbatch<<<64, 256, 0, stream>>>(x, XB);
  k_gcn_gemm<<<256, 256, 0, stream>>>(XB, gl_embed, gcn_w, HRAW);
  k_gcn_agg<<<1024, 256, 0, stream>>>(HRAW, GLOFF, GLLIST, COEF, gcn_b, HA);
  k_mlp1<<<256, 256, 0, stream>>>(HA, mlp_w1, mlp_b1, HMID);
  k_mlp2<<<256, 256, 0, stream>>>(HMID, mlp_w2, mlp_b2, XB, XREC, XS);
  k_rec_t<<<64, 256, 0, stream>>>(XREC, out_rec);
  k_lr<<<2048, 256, 0, stream>>>(XS, ta_w, ta_b, LEFT, RIGHT);
  k_escore<<<128, 512, 0, stream>>>(LEFT, RIGHT, ta_a, ta_bias, G);
  k_softpv<<<256, 256, 0, stream>>>(G, XS, HT);
  k_gatgemm<<<256, 256, 0, stream>>>(HT, gat_w, gat_asrc, gat_adst, H2, SSRC, SDST);
  k_gatagg<<<1024, 256, 0, stream>>>(H2, SSRC, SDST, GATOFF, GATLIST, gat_b, fc_w, fc_b, out_pre);
}

// Round 2
// 136.753 us; speedup vs baseline: 1.5319x; 1.5319x over previous
//
#include <hip/hip_runtime.h>
#include <math.h>

#define BB  64
#define WW  128
#define NN  64
#define HIDN 77

// ---------------- K0: CSR build (single block) ----------------
__global__ __launch_bounds__(256) void k_csr(const int* __restrict__ gl_ei, int E_gl,
                                             const int* __restrict__ gat_ei, int E_gat,
                                             int* __restrict__ gl_off, int* __restrict__ gl_list,
                                             float* __restrict__ gl_coef,
                                             int* __restrict__ gat_off, int* __restrict__ gat_list) {
  __shared__ int cnt[64], offs[65], cur[64];
  __shared__ int lst[2048];
  __shared__ float dv[64];
  int tid = threadIdx.x;

  if (tid < 64) cnt[tid] = 1;
  __syncthreads();
  for (int e = tid; e < E_gl; e += 256) atomicAdd(&cnt[gl_ei[BB * E_gl + e]], 1);
  __syncthreads();
  if (tid == 0) { int s = 0; for (int n = 0; n < 64; n++) { offs[n] = s; s += cnt[n]; } offs[64] = s; }
  __syncthreads();
  if (tid < 64) { cur[tid] = offs[tid]; dv[tid] = rsqrtf((float)cnt[tid]); }
  __syncthreads();
  for (int e = tid; e < E_gl; e += 256) {
    int src = gl_ei[e];
    int dst = gl_ei[BB * E_gl + e];
    int pos = atomicAdd(&cur[dst], 1);
    lst[pos] = src;
  }
  if (tid < 64) { int pos = atomicAdd(&cur[tid], 1); lst[pos] = tid; }
  __syncthreads();
  int totG = offs[64];
  if (tid < 65) gl_off[tid] = offs[tid];
  for (int i = tid; i < totG; i += 256) gl_list[i] = lst[i];
  if (tid < 64) {
    float dn = dv[tid];
    for (int e = offs[tid]; e < offs[tid + 1]; e++) gl_coef[e] = dv[lst[e]] * dn;
  }
  __syncthreads();

  if (tid < 64) cnt[tid] = 1;
  __syncthreads();
  for (int e = tid; e < E_gat; e += 256) atomicAdd(&cnt[gat_ei[BB * E_gat + e]], 1);
  __syncthreads();
  if (tid == 0) { int s = 0; for (int n = 0; n < 64; n++) { offs[n] = s; s += cnt[n]; } offs[64] = s; }
  __syncthreads();
  if (tid < 64) cur[tid] = offs[tid];
  __syncthreads();
  for (int e = tid; e < E_gat; e += 256) {
    int src = gat_ei[e];
    int dst = gat_ei[BB * E_gat + e];
    int pos = atomicAdd(&cur[dst], 1);
    lst[pos] = src;
  }
  if (tid < 64) { int pos = atomicAdd(&cur[tid], 1); lst[pos] = tid; }
  __syncthreads();
  int totA = offs[64];
  if (tid < 65) gat_off[tid] = offs[tid];
  for (int i = tid; i < totA; i += 256) gat_list[i] = lst[i];
}

// ---------------- K1: hraw = [x^T | emb] @ gcn_w  (LDS-tiled) ----------------
// 16 rows/block, grid 256. Reads x transposed directly (16 consecutive n = 64B/w).
#define AS_STR 146
__global__ __launch_bounds__(256) void k_gcn_gemm(const float* __restrict__ x, const float* __restrict__ emb,
                                                  const float* __restrict__ wg, float* __restrict__ hraw) {
  __shared__ float Ws[140 * 128];   // 71680 B
  __shared__ float As[16 * AS_STR]; // 9344 B
  int tid = threadIdx.x;
  int r0 = blockIdx.x * 16;
  int b = r0 >> 6, n0 = r0 & 63;
  const float4* W4 = (const float4*)wg;
  float4* Ws4 = (float4*)Ws;
  for (int t = tid; t < 4480; t += 256) Ws4[t] = W4[t];
  const float* xb = x + (size_t)b * 8192 + n0;
  for (int t = tid; t < 2048; t += 256) {
    int w = t >> 4, i = t & 15;
    As[i * AS_STR + w] = xb[w * 64 + i];
  }
  if (tid < 192) {
    int i = tid / 12, jj = tid % 12;
    As[i * AS_STR + 128 + jj] = emb[(n0 + i) * 12 + jj];
  }
  __syncthreads();
  int tx = tid & 31, ty = tid >> 5;
  int row0 = ty * 2;
  float acc0[4] = {0, 0, 0, 0}, acc1[4] = {0, 0, 0, 0};
  const float* A0 = As + row0 * AS_STR;
  const float* A1 = A0 + AS_STR;
#pragma unroll 4
  for (int k = 0; k < 140; k++) {
    float4 wv = *(const float4*)&Ws[k * 128 + tx * 4];
    float a0 = A0[k], a1 = A1[k];
    acc0[0] += a0 * wv.x; acc0[1] += a0 * wv.y; acc0[2] += a0 * wv.z; acc0[3] += a0 * wv.w;
    acc1[0] += a1 * wv.x; acc1[1] += a1 * wv.y; acc1[2] += a1 * wv.z; acc1[3] += a1 * wv.w;
  }
  float* o = hraw + (size_t)(r0 + row0) * 128 + tx * 4;
  *(float4*)o = make_float4(acc0[0], acc0[1], acc0[2], acc0[3]);
  *(float4*)(o + 128) = make_float4(acc1[0], acc1[1], acc1[2], acc1[3]);
}

// ---------------- K2: GCN aggregate (register edge list + shfl) ----------------
__global__ __launch_bounds__(256) void k_gcn_agg(const float* __restrict__ hraw, const int* __restrict__ off,
                                                 const int* __restrict__ list, const float* __restrict__ coef,
                                                 const float* __restrict__ bias, float* __restrict__ hA) {
  int wave = threadIdx.x >> 6, lane = threadIdx.x & 63;
  int r = blockIdx.x * 4 + wave;
  int b = r >> 6, n = r & 63, c = lane * 2;
  int e0 = off[n], e1 = off[n + 1];
  int deg = e1 - e0, m = deg < 64 ? deg : 64;
  int el = 0; float cf = 0.f;
  if (lane < m) { el = list[e0 + lane]; cf = coef[e0 + lane]; }
  const float* base = hraw + (size_t)b * 8192;
  float ax = 0.f, ay = 0.f;
  for (int e = 0; e < m; e++) {
    int s = __shfl(el, e); float w = __shfl(cf, e);
    float2 h = *(const float2*)&base[s * 128 + c];
    ax += w * h.x; ay += w * h.y;
  }
  for (int e = e0 + 64; e < e1; e++) {
    int s = list[e]; float w = coef[e];
    float2 h = *(const float2*)&base[s * 128 + c];
    ax += w * h.x; ay += w * h.y;
  }
  ax = fmaxf(ax + bias[c], 0.f);
  ay = fmaxf(ay + bias[c + 1], 0.f);
  *(float2*)&hA[(size_t)r * 128 + c] = make_float2(ax, ay);
}

// ---------------- K3: fused MLP: hA -> hmid(LDS) -> x_rec -> out_rec + xs ----------------
__global__ __launch_bounds__(256) void k_mlp(const float* __restrict__ hA, const float* __restrict__ w1,
                                             const float* __restrict__ b1, const float* __restrict__ w2,
                                             const float* __restrict__ b2, const float* __restrict__ x,
                                             float* __restrict__ xs, float* __restrict__ out_rec) {
  __shared__ float smem[25600];      // 100 KB
  float* As1 = smem;                 // 16*132 = 2112
  float* W1s = smem + 2112;          // 128*80 = 10240
  float* hm  = smem + 12352;         // 16*80  = 1280
  float* W2s = smem + 13632;         // 77*128 = 9856
  float* xbt = smem + 23488;         // 16*132 = 2112
  float* recT = smem + 2112;         // reuse W1s region: 128*17 = 2176

  int tid = threadIdx.x;
  int r0 = blockIdx.x * 16;
  int b = r0 >> 6, n0 = r0 & 63;

  for (int t = tid; t < 2048; t += 256) {  // As1: hA tile (coalesced)
    int i = t >> 7, k = t & 127;
    As1[i * 132 + k] = hA[(size_t)(r0 + i) * 128 + k];
  }
  for (int t = tid; t < 10240; t += 256) { // W1s padded 80
    int k = t / 80, c = t % 80;
    W1s[t] = (c < HIDN) ? w1[k * HIDN + c] : 0.f;
  }
  {
    const float4* w24 = (const float4*)w2;
    float4* W2s4 = (float4*)W2s;
    for (int t = tid; t < 2464; t += 256) W2s4[t] = w24[t];
  }
  const float* xb = x + (size_t)b * 8192 + n0;
  for (int t = tid; t < 2048; t += 256) {  // x tile (transposed read)
    int w = t >> 4, i = t & 15;
    xbt[i * 132 + w] = xb[w * 64 + i];
  }
  __syncthreads();

  int tx = tid & 31, ty = tid >> 5;
  int row0 = ty * 2;
  int c0 = tx * 4;
  bool act = c0 < HIDN;
  int cW = act ? c0 : 0;

  // phase 1: hmid = tanh(hA @ w1 + b1)
  {
    float a00 = 0, a01 = 0, a02 = 0, a03 = 0, a10 = 0, a11 = 0, a12 = 0, a13 = 0;
    const float* A0 = As1 + row0 * 132;
    const float* A1 = A0 + 132;
#pragma unroll 4
    for (int k = 0; k < 128; k++) {
      float4 wv = *(const float4*)&W1s[k * 80 + cW];
      float a0 = A0[k], a1 = A1[k];
      a00 += a0 * wv.x; a01 += a0 * wv.y; a02 += a0 * wv.z; a03 += a0 * wv.w;
      a10 += a1 * wv.x; a11 += a1 * wv.y; a12 += a1 * wv.z; a13 += a1 * wv.w;
    }
    if (act) {
      float r0v[4] = {a00, a01, a02, a03}, r1v[4] = {a10, a11, a12, a13};
#pragma unroll
      for (int j = 0; j < 4; j++) {
        if (c0 + j < HIDN) {
          float bb = b1[c0 + j];
          hm[row0 * 80 + c0 + j] = tanhf(r0v[j] + bb);
          hm[(row0 + 1) * 80 + c0 + j] = tanhf(r1v[j] + bb);
        }
      }
    }
  }
  __syncthreads();

  // phase 2: x_rec = tanh(hm @ w2 + b2); xs = x + x_rec; recT for out_rec
  {
    float a00 = 0, a01 = 0, a02 = 0, a03 = 0, a10 = 0, a11 = 0, a12 = 0, a13 = 0;
    const float* H0 = hm + row0 * 80;
    const float* H1 = H0 + 80;
#pragma unroll 4
    for (int k = 0; k < HIDN; k++) {
      float4 wv = *(const float4*)&W2s[k * 128 + c0];
      float a0 = H0[k], a1 = H1[k];
      a00 += a0 * wv.x; a01 += a0 * wv.y; a02 += a0 * wv.z; a03 += a0 * wv.w;
      a10 += a1 * wv.x; a11 += a1 * wv.y; a12 += a1 * wv.z; a13 += a1 * wv.w;
    }
    float4 bv = *(const float4*)&b2[c0];
    float x00 = tanhf(a00 + bv.x), x01 = tanhf(a01 + bv.y), x02 = tanhf(a02 + bv.z), x03 = tanhf(a03 + bv.w);
    float x10 = tanhf(a10 + bv.x), x11 = tanhf(a11 + bv.y), x12 = tanhf(a12 + bv.z), x13 = tanhf(a13 + bv.w);
    const float* X0 = xbt + row0 * 132;
    const float* X1 = X0 + 132;
    float4 s0 = make_float4(X0[c0] + x00, X0[c0 + 1] + x01, X0[c0 + 2] + x02, X0[c0 + 3] + x03);
    float4 s1 = make_float4(X1[c0] + x10, X1[c0 + 1] + x11, X1[c0 + 2] + x12, X1[c0 + 3] + x13);
    *(float4*)&xs[(size_t)(r0 + row0) * 128 + c0] = s0;
    *(float4*)&xs[(size_t)(r0 + row0 + 1) * 128 + c0] = s1;
    // recT[w][i] (writes over dead W1s after the barrier above)
    recT[(c0 + 0) * 17 + row0] = x00; recT[(c0 + 1) * 17 + row0] = x01;
    recT[(c0 + 2) * 17 + row0] = x02; recT[(c0 + 3) * 17 + row0] = x03;
    recT[(c0 + 0) * 17 + row0 + 1] = x10; recT[(c0 + 1) * 17 + row0 + 1] = x11;
    recT[(c0 + 2) * 17 + row0 + 1] = x12; recT[(c0 + 3) * 17 + row0 + 1] = x13;
  }
  __syncthreads();
  float* orc = out_rec + (size_t)b * 8192 + n0;
  for (int t = tid; t < 2048; t += 256) {
    int w = t >> 4, i = t & 15;
    orc[w * 64 + i] = recT[w * 17 + i];
  }
}

// ---------------- K4: left/right projections (ta_b folded into left) ----------------
__global__ __launch_bounds__(256) void k_lr(const float* __restrict__ xs, const float* __restrict__ ta_w,
                                            const float* __restrict__ ta_b, float* __restrict__ leftT,
                                            float* __restrict__ rightT) {
  int wave = threadIdx.x >> 6, lane = threadIdx.x & 63;
  int idx = blockIdx.x * 4 + wave;
  int b = idx >> 7, e = idx & 127;
  int c = lane * 2;
  const float* xsb = xs + (size_t)b * 8192;
  float lx = 0, ly = 0, rx = 0, ry = 0;
#pragma unroll 4
  for (int n = 0; n < 64; n++) {
    float wl = ta_w[n * 128 + e];
    float wr = ta_w[(64 + n) * 128 + e];
    float2 xv = *(const float2*)&xsb[n * 128 + c];
    lx += wl * xv.x; ly += wl * xv.y;
    rx += wr * xv.x; ry += wr * xv.y;
  }
  float tb = ta_b[e];
  *(float2*)&leftT[((size_t)b * 128 + e) * 128 + c] = make_float2(lx + tb, ly + tb);
  *(float2*)&rightT[((size_t)b * 128 + e) * 128 + c] = make_float2(rx, ry);
}

// ---------------- K5: fused e-score + softmax + PV + tanh -> ht ----------------
// grid 256 = b(64) x i-quarter(4); block 512.
__global__ __launch_bounds__(512) void k_attn(const float* __restrict__ LEFT_, const float* __restrict__ RIGHT_,
                                              const float* __restrict__ ta_a, const float* __restrict__ ta_bias,
                                              const float* __restrict__ xs, float* __restrict__ ht) {
  __shared__ float Rf[128 * 128];   // 64 KB
  __shared__ float Lh[32 * 132];    // 16.5 KB (e-phase uses [128][32]; reused as P[32][132])
  __shared__ float xsT[128 * 68];   // 34 KB
  __shared__ float c1[128], c2[128];
  int tid = threadIdx.x;
  int b = blockIdx.x >> 2, q = blockIdx.x & 3;
  int i0 = q * 32;

  {
    const float4* R4 = (const float4*)(RIGHT_ + (size_t)b * 16384);
    float4* Rf4 = (float4*)Rf;
#pragma unroll
    for (int t = 0; t < 8; t++) Rf4[tid + t * 512] = R4[tid + t * 512];
  }
  {
    const float* Lp = LEFT_ + (size_t)b * 16384 + i0;
#pragma unroll
    for (int t = 0; t < 8; t++) {
      int idx = tid + t * 512;
      Lh[idx] = Lp[(idx >> 5) * 128 + (idx & 31)];
    }
  }
  {
    const float* xsb = xs + (size_t)b * 8192;
#pragma unroll
    for (int t = 0; t < 16; t++) {
      int idx = tid + t * 512;
      xsT[(idx & 127) * 68 + (idx >> 7)] = xsb[idx];
    }
  }
  if (tid < 128) { float a = ta_a[tid]; c1[tid] = 0.6f * a; c2[tid] = 0.4f * a; }
  __syncthreads();

  int tj = tid & 31, ti = tid >> 5;  // ti 0..15 (each 2 i-rows); half-wave = one ti
  float acc[2][4];
#pragma unroll
  for (int a = 0; a < 2; a++)
#pragma unroll
    for (int j = 0; j < 4; j++) acc[a][j] = 0.f;

#pragma unroll 2
  for (int e = 0; e < 128; e++) {
    float2 L = *(const float2*)&Lh[e * 32 + ti * 2];
    float4 R = *(const float4*)&Rf[e * 128 + tj * 4];
    float k1 = c1[e], k2 = c2[e];
    float Ra[4] = {R.x, R.y, R.z, R.w};
    float La[2] = {L.x, L.y};
#pragma unroll
    for (int a = 0; a < 2; a++)
#pragma unroll
      for (int j = 0; j < 4; j++) {
        float t = La[a] + Ra[j];
        acc[a][j] += k1 * t + k2 * fabsf(t);  // = leaky(t)*a_e
      }
  }

  // bias + row softmax (row spread over one 32-lane half-wave)
  float p[2][4];
#pragma unroll
  for (int a = 0; a < 2; a++) {
    int i = i0 + ti * 2 + a;
    float4 bv = *(const float4*)&ta_bias[(size_t)i * 128 + tj * 4];
    float v0 = acc[a][0] + bv.x, v1 = acc[a][1] + bv.y, v2 = acc[a][2] + bv.z, v3 = acc[a][3] + bv.w;
    float m = fmaxf(fmaxf(v0, v1), fmaxf(v2, v3));
#pragma unroll
    for (int o = 16; o > 0; o >>= 1) m = fmaxf(m, __shfl_xor(m, o));
    float e0 = __expf(v0 - m), e1 = __expf(v1 - m), e2 = __expf(v2 - m), e3 = __expf(v3 - m);
    float s = e0 + e1 + e2 + e3;
#pragma unroll
    for (int o = 16; o > 0; o >>= 1) s += __shfl_xor(s, o);
    float inv = 1.f / s;
    p[a][0] = e0 * inv; p[a][1] = e1 * inv; p[a][2] = e2 * inv; p[a][3] = e3 * inv;
  }
  __syncthreads();
  float* P = Lh;  // [32][132]
  *(float4*)&P[(ti * 2 + 0) * 132 + tj * 4] = make_float4(p[0][0], p[0][1], p[0][2], p[0][3]);
  *(float4*)&P[(ti * 2 + 1) * 132 + tj * 4] = make_float4(p[1][0], p[1][1], p[1][2], p[1][3]);
  __syncthreads();

  // PV: ht[i][n] = sum_j P[i][j] * xsT[j][n]; thread = 1 i x 4 n
  int tn = tid & 15, i2 = tid >> 4;
  float o0 = 0, o1 = 0, o2 = 0, o3 = 0;
  const float* Prow = P + i2 * 132;
#pragma unroll 4
  for (int j = 0; j < 128; j++) {
    float4 xv = *(const float4*)&xsT[j * 68 + tn * 4];
    float pv = Prow[j];
    o0 += pv * xv.x; o1 += pv * xv.y; o2 += pv * xv.z; o3 += pv * xv.w;
  }
  float* hto = ht + (size_t)b * 8192 + (size_t)(i0 + i2) * 64 + tn * 4;
  *(float4*)hto = make_float4(tanhf(o0), tanhf(o1), tanhf(o2), tanhf(o3));
}

// ---------------- K6: h2 = hg @ gat_w (LDS-tiled) + ssrc/sdst ----------------
__global__ __launch_bounds__(256) void k_gatgemm(const float* __restrict__ ht, const float* __restrict__ gw,
                                                 const float* __restrict__ asrc, const float* __restrict__ adst,
                                                 float* __restrict__ h2, float* __restrict__ ssrc,
                                                 float* __restrict__ sdst) {
  __shared__ float Ws[128 * 128];  // 64 KB
  __shared__ float As[16 * 132];   // 8448 B
  int tid = threadIdx.x;
  int r0 = blockIdx.x * 16;
  int b = r0 >> 6, n0 = r0 & 63;
  {
    const float4* W4 = (const float4*)gw;
    float4* Ws4 = (float4*)Ws;
    for (int t = tid; t < 4096; t += 256) Ws4[t] = W4[t];
  }
  const float* hb = ht + (size_t)b * 8192 + n0;
  for (int t = tid; t < 2048; t += 256) {
    int k = t >> 4, i = t & 15;
    As[i * 132 + k] = hb[k * 64 + i];
  }
  __syncthreads();
  int tx = tid & 31, ty = tid >> 5;
  int row0 = ty * 2;
  int c0 = tx * 4;
  float a00 = 0, a01 = 0, a02 = 0, a03 = 0, a10 = 0, a11 = 0, a12 = 0, a13 = 0;
  const float* A0 = As + row0 * 132;
  const float* A1 = A0 + 132;
#pragma unroll 4
  for (int k = 0; k < 128; k++) {
    float4 wv = *(const float4*)&Ws[k * 128 + c0];
    float a0 = A0[k], a1 = A1[k];
    a00 += a0 * wv.x; a01 += a0 * wv.y; a02 += a0 * wv.z; a03 += a0 * wv.w;
    a10 += a1 * wv.x; a11 += a1 * wv.y; a12 += a1 * wv.z; a13 += a1 * wv.w;
  }
  float4 as4 = *(const float4*)&asrc[c0];
  float4 ad4 = *(const float4*)&adst[c0];
  float* o = h2 + (size_t)(r0 + row0) * 128 + c0;
  *(float4*)o = make_float4(a00, a01, a02, a03);
  *(float4*)(o + 128) = make_float4(a10, a11, a12, a13);
  float ss0 = a00 * as4.x + a01 * as4.y + a02 * as4.z + a03 * as4.w;
  float sd0 = a00 * ad4.x + a01 * ad4.y + a02 * ad4.z + a03 * ad4.w;
  float ss1 = a10 * as4.x + a11 * as4.y + a12 * as4.z + a13 * as4.w;
  float sd1 = a10 * ad4.x + a11 * ad4.y + a12 * ad4.z + a13 * ad4.w;
#pragma unroll
  for (int o2 = 16; o2 > 0; o2 >>= 1) {
    ss0 += __shfl_xor(ss0, o2); sd0 += __shfl_xor(sd0, o2);
    ss1 += __shfl_xor(ss1, o2); sd1 += __shfl_xor(sd1, o2);
  }
  if (tx == 0) {
    ssrc[r0 + row0] = ss0; sdst[r0 + row0] = sd0;
    ssrc[r0 + row0 + 1] = ss1; sdst[r0 + row0 + 1] = sd1;
  }
}

// ---------------- K7: GAT edge-softmax aggregate + fused FC + tanh ----------------
__global__ __launch_bounds__(256) void k_gatagg(const float* __restrict__ h2, const float* __restrict__ ssrc,
                                                const float* __restrict__ sdst, const int* __restrict__ off,
                                                const int* __restrict__ list, const float* __restrict__ gb,
                                                const float* __restrict__ fcw, const float* __restrict__ fcb,
                                                float* __restrict__ outp) {
  int wave = threadIdx.x >> 6, lane = threadIdx.x & 63;
  int r = blockIdx.x * 4 + wave;
  int b = r >> 6, n = r & 63, c = lane * 2;
  int e0 = off[n], e1 = off[n + 1];
  int deg = e1 - e0, m = deg < 64 ? deg : 64;
  const float* sb = ssrc + b * 64;
  float sd = sdst[r];
  int el = 0; float evl = -1e30f;
  if (lane < m) {
    el = list[e0 + lane];
    float t = sb[el] + sd;
    evl = fmaxf(t, 0.2f * t);
  }
  float mx = evl;
#pragma unroll
  for (int o = 32; o > 0; o >>= 1) mx = fmaxf(mx, __shfl_xor(mx, o));
  for (int e = e0 + 64; e < e1; e++) {
    int s = list[e]; float t = sb[s] + sd; t = fmaxf(t, 0.2f * t);
    mx = fmaxf(mx, t);
  }
  float wl = (lane < m) ? __expf(evl - mx) : 0.f;
  float den = wl;
#pragma unroll
  for (int o = 32; o > 0; o >>= 1) den += __shfl_xor(den, o);
  const float* hb = h2 + (size_t)b * 8192;
  float ax = 0.f, ay = 0.f;
  for (int e = 0; e < m; e++) {
    int s = __shfl(el, e); float w = __shfl(wl, e);
    float2 h = *(const float2*)&hb[s * 128 + c];
    ax += w * h.x; ay += w * h.y;
  }
  for (int e = e0 + 64; e < e1; e++) {
    int s = list[e]; float t = sb[s] + sd; t = fmaxf(t, 0.2f * t);
    float w = __expf(t - mx);
    den += w;
    float2 h = *(const float2*)&hb[s * 128 + c];
    ax += w * h.x; ay += w * h.y;
  }
  float inv = 1.f / den;
  float o0 = ax * inv + gb[c], o1 = ay * inv + gb[c + 1];
  float xp = o0 * fcw[c] + o1 * fcw[c + 1];
#pragma unroll
  for (int o2 = 32; o2 > 0; o2 >>= 1) xp += __shfl_xor(xp, o2);
  if (lane == 0) outp[r] = tanhf(xp + fcb[0]);
}

extern "C" void kernel_launch(void* const* d_in, const int* in_sizes, int n_in,
                              void* d_out, int out_size, void* d_ws, size_t ws_size,
                              hipStream_t stream) {
  (void)n_in; (void)out_size; (void)ws_size;
  const float* x        = (const float*)d_in[0];
  const float* gl_embed = (const float*)d_in[7];
  const float* gcn_w    = (const float*)d_in[8];
  const float* gcn_b    = (const float*)d_in[9];
  const float* mlp_w1   = (const float*)d_in[10];
  const float* mlp_b1   = (const float*)d_in[11];
  const float* mlp_w2   = (const float*)d_in[12];
  const float* mlp_b2   = (const float*)d_in[13];
  const float* ta_w     = (const float*)d_in[14];
  const float* ta_b     = (const float*)d_in[15];
  const float* ta_a     = (const float*)d_in[16];
  const float* ta_bias  = (const float*)d_in[17];
  const float* gat_w    = (const float*)d_in[18];
  const float* gat_asrc = (const float*)d_in[19];
  const float* gat_adst = (const float*)d_in[20];
  const float* gat_b    = (const float*)d_in[21];
  const float* fc_w     = (const float*)d_in[22];
  const float* fc_b     = (const float*)d_in[23];
  const int*   gat_ei   = (const int*)d_in[24];
  const int*   gl_ei    = (const int*)d_in[25];

  int E_gat = in_sizes[24] / (2 * BB);  // 1280
  int E_gl  = in_sizes[25] / (2 * BB);  // 1638

  float* ws = (float*)d_ws;
  float* HRAW  = ws + 0;        // 524288
  float* HA    = ws + 524288;   // 524288
  float* XS    = ws + 1048576;  // 524288
  float* LEFT  = ws + 1572864;  // 1048576
  float* RIGHT = ws + 2621440;  // 1048576
  float* HT    = ws + 3670016;  // 524288
  float* H2    = ws + 4194304;  // 524288
  float* SSRC  = ws + 4718592;  // 4096
  float* SDST  = ws + 4722688;  // 4096
  float* COEF  = ws + 4726784;  // 2048
  int*   IP    = (int*)(ws + 4728832);
  int* GLOFF   = IP;            // 72
  int* GLLIST  = IP + 72;       // 2048
  int* GATOFF  = IP + 2120;     // 72
  int* GATLIST = IP + 2192;     // 2048

  float* out_rec = (float*)d_out;
  float* out_pre = (float*)d_out + 524288;

  k_csr<<<1, 256, 0, stream>>>(gl_ei, E_gl, gat_ei, E_gat, GLOFF, GLLIST, COEF, GATOFF, GATLIST);
  k_gcn_gemm<<<256, 256, 0, stream>>>(x, gl_embed, gcn_w, HRAW);
  k_gcn_agg<<<1024, 256, 0, stream>>>(HRAW, GLOFF, GLLIST, COEF, gcn_b, HA);
  k_mlp<<<256, 256, 0, stream>>>(HA, mlp_w1, mlp_b1, mlp_w2, mlp_b2, x, XS, out_rec);
  k_lr<<<2048, 256, 0, stream>>>(XS, ta_w, ta_b, LEFT, RIGHT);
  k_attn<<<256, 512, 0, stream>>>(LEFT, RIGHT, ta_a, ta_bias, XS, HT);
  k_gatgemm<<<256, 256, 0, stream>>>(HT, gat_w, gat_asrc, gat_adst, H2, SSRC, SDST);
  k_gatagg<<<1024, 256, 0, stream>>>(H2, SSRC, SDST, GATOFF, GATLIST, gat_b, fc_w, fc_b, out_pre);
}

// Round 3
// 123.339 us; speedup vs baseline: 1.6985x; 1.1088x over previous
//
#include <hip/hip_runtime.h>
#include <math.h>

#define BB  64
#define WW  128
#define NN  64
#define HIDN 77
#define AS_STR 146

// ---------------- K1: hraw = [x^T | emb] @ gcn_w  (LDS-tiled) + CSR side-work in blocks 0/1 ----------------
__global__ __launch_bounds__(256) void k_gemm_csr(const float* __restrict__ x, const float* __restrict__ emb,
                                                  const float* __restrict__ wg,
                                                  const int* __restrict__ gl_ei, int E_gl,
                                                  const int* __restrict__ gat_ei, int E_gat,
                                                  float* __restrict__ hraw,
                                                  int* __restrict__ gl_off, int* __restrict__ gl_list,
                                                  float* __restrict__ gl_coef,
                                                  int* __restrict__ gat_off, int* __restrict__ gat_list) {
  __shared__ float Ws[140 * 128];   // 71680 B
  __shared__ float As[16 * AS_STR]; // 9344 B
  __shared__ int cnt[64], offs[65], cur[64];
  __shared__ int lst[2048];
  __shared__ float dvv[64];
  int tid = threadIdx.x;
  int r0 = blockIdx.x * 16;
  int b = r0 >> 6, n0 = r0 & 63;
  const float4* W4 = (const float4*)wg;
  float4* Ws4 = (float4*)Ws;
  for (int t = tid; t < 4480; t += 256) Ws4[t] = W4[t];
  const float* xb = x + (size_t)b * 8192 + n0;
  for (int t = tid; t < 2048; t += 256) {
    int w = t >> 4, i = t & 15;
    As[i * AS_STR + w] = xb[w * 64 + i];
  }
  if (tid < 192) {
    int i = tid / 12, jj = tid % 12;
    As[i * AS_STR + 128 + jj] = emb[(n0 + i) * 12 + jj];
  }
  __syncthreads();
  int tx = tid & 31, ty = tid >> 5;
  int row0 = ty * 2;
  float acc0[4] = {0, 0, 0, 0}, acc1[4] = {0, 0, 0, 0};
  const float* A0 = As + row0 * AS_STR;
  const float* A1 = A0 + AS_STR;
#pragma unroll 4
  for (int k = 0; k < 140; k++) {
    float4 wv = *(const float4*)&Ws[k * 128 + tx * 4];
    float a0 = A0[k], a1 = A1[k];
    acc0[0] += a0 * wv.x; acc0[1] += a0 * wv.y; acc0[2] += a0 * wv.z; acc0[3] += a0 * wv.w;
    acc1[0] += a1 * wv.x; acc1[1] += a1 * wv.y; acc1[2] += a1 * wv.z; acc1[3] += a1 * wv.w;
  }
  float* o = hraw + (size_t)(r0 + row0) * 128 + tx * 4;
  *(float4*)o = make_float4(acc0[0], acc0[1], acc0[2], acc0[3]);
  *(float4*)(o + 128) = make_float4(acc1[0], acc1[1], acc1[2], acc1[3]);

  // ---- CSR side-work (block 0: GL incl. GCN coefs; block 1: GAT) ----
  if (blockIdx.x == 0) {
    if (tid < 64) cnt[tid] = 1;  // self loop
    __syncthreads();
    for (int e = tid; e < E_gl; e += 256) atomicAdd(&cnt[gl_ei[BB * E_gl + e]], 1);
    __syncthreads();
    if (tid == 0) { int s = 0; for (int n = 0; n < 64; n++) { offs[n] = s; s += cnt[n]; } offs[64] = s; }
    __syncthreads();
    if (tid < 64) { cur[tid] = offs[tid]; dvv[tid] = rsqrtf((float)cnt[tid]); }
    __syncthreads();
    for (int e = tid; e < E_gl; e += 256) {
      int src = gl_ei[e], dst = gl_ei[BB * E_gl + e];
      lst[atomicAdd(&cur[dst], 1)] = src;
    }
    if (tid < 64) lst[atomicAdd(&cur[tid], 1)] = tid;
    __syncthreads();
    if (tid < 65) gl_off[tid] = offs[tid];
    int tot = offs[64];
    for (int i2 = tid; i2 < tot; i2 += 256) gl_list[i2] = lst[i2];
    if (tid < 64) {
      float dn = dvv[tid];
      for (int e = offs[tid]; e < offs[tid + 1]; e++) gl_coef[e] = dvv[lst[e]] * dn;
    }
  } else if (blockIdx.x == 1) {
    if (tid < 64) cnt[tid] = 1;
    __syncthreads();
    for (int e = tid; e < E_gat; e += 256) atomicAdd(&cnt[gat_ei[BB * E_gat + e]], 1);
    __syncthreads();
    if (tid == 0) { int s = 0; for (int n = 0; n < 64; n++) { offs[n] = s; s += cnt[n]; } offs[64] = s; }
    __syncthreads();
    if (tid < 64) cur[tid] = offs[tid];
    __syncthreads();
    for (int e = tid; e < E_gat; e += 256) {
      int src = gat_ei[e], dst = gat_ei[BB * E_gat + e];
      lst[atomicAdd(&cur[dst], 1)] = src;
    }
    if (tid < 64) lst[atomicAdd(&cur[tid], 1)] = tid;
    __syncthreads();
    if (tid < 65) gat_off[tid] = offs[tid];
    int tot = offs[64];
    for (int i2 = tid; i2 < tot; i2 += 256) gat_list[i2] = lst[i2];
  }
}

// ---------------- K2: fused GCN-aggregate + MLP -> xs, out_rec ----------------
__global__ __launch_bounds__(256) void k_aggmlp(const float* __restrict__ hraw, const int* __restrict__ off,
                                                const int* __restrict__ list, const float* __restrict__ coef,
                                                const float* __restrict__ gcn_b,
                                                const float* __restrict__ w1, const float* __restrict__ b1,
                                                const float* __restrict__ w2, const float* __restrict__ b2,
                                                const float* __restrict__ x,
                                                float* __restrict__ xs, float* __restrict__ out_rec) {
  __shared__ float smem[25600];      // 100 KB
  float* As1 = smem;                 // 16*132
  float* W1s = smem + 2112;          // 128*80
  float* hm  = smem + 12352;         // 16*80
  float* W2s = smem + 13632;         // 77*128
  float* xbt = smem + 23488;         // 16*132
  float* recT = smem + 2112;         // reuse W1s after phase1

  int tid = threadIdx.x;
  int r0 = blockIdx.x * 16;
  int b = r0 >> 6, n0 = r0 & 63;

  for (int t = tid; t < 10240; t += 256) {
    int k = t / 80, c = t % 80;
    W1s[t] = (c < HIDN) ? w1[k * HIDN + c] : 0.f;
  }
  {
    const float4* w24 = (const float4*)w2;
    float4* W2s4 = (float4*)W2s;
    for (int t = tid; t < 2464; t += 256) W2s4[t] = w24[t];
  }
  const float* xb = x + (size_t)b * 8192 + n0;
  for (int t = tid; t < 2048; t += 256) {
    int w = t >> 4, i = t & 15;
    xbt[i * 132 + w] = xb[w * 64 + i];
  }

  // GCN aggregate directly into As1 (thread = 1 row x 8 cols)
  {
    int i = tid >> 4, tc = tid & 15;
    int n = n0 + i;
    int e0 = off[n], e1 = off[n + 1];
    const float* base = hraw + (size_t)b * 8192 + tc * 8;
    float a0 = 0, a1 = 0, a2 = 0, a3 = 0, a4 = 0, a5 = 0, a6 = 0, a7 = 0;
    for (int e = e0; e < e1; e++) {
      int s = list[e]; float cf = coef[e];
      float4 h0 = *(const float4*)(base + s * 128);
      float4 h1 = *(const float4*)(base + s * 128 + 4);
      a0 += cf * h0.x; a1 += cf * h0.y; a2 += cf * h0.z; a3 += cf * h0.w;
      a4 += cf * h1.x; a5 += cf * h1.y; a6 += cf * h1.z; a7 += cf * h1.w;
    }
    const float* gbp = gcn_b + tc * 8;
    float* dst = As1 + i * 132 + tc * 8;
    dst[0] = fmaxf(a0 + gbp[0], 0.f); dst[1] = fmaxf(a1 + gbp[1], 0.f);
    dst[2] = fmaxf(a2 + gbp[2], 0.f); dst[3] = fmaxf(a3 + gbp[3], 0.f);
    dst[4] = fmaxf(a4 + gbp[4], 0.f); dst[5] = fmaxf(a5 + gbp[5], 0.f);
    dst[6] = fmaxf(a6 + gbp[6], 0.f); dst[7] = fmaxf(a7 + gbp[7], 0.f);
  }
  __syncthreads();

  int tx = tid & 31, ty = tid >> 5;
  int row0 = ty * 2;
  int c0 = tx * 4;
  bool act = c0 < HIDN;
  int cW = act ? c0 : 0;

  // phase 1: hmid = tanh(hA @ w1 + b1)
  {
    float a00 = 0, a01 = 0, a02 = 0, a03 = 0, a10 = 0, a11 = 0, a12 = 0, a13 = 0;
    const float* A0 = As1 + row0 * 132;
    const float* A1 = A0 + 132;
#pragma unroll 4
    for (int k = 0; k < 128; k++) {
      float4 wv = *(const float4*)&W1s[k * 80 + cW];
      float a0 = A0[k], a1 = A1[k];
      a00 += a0 * wv.x; a01 += a0 * wv.y; a02 += a0 * wv.z; a03 += a0 * wv.w;
      a10 += a1 * wv.x; a11 += a1 * wv.y; a12 += a1 * wv.z; a13 += a1 * wv.w;
    }
    if (act) {
      float r0v[4] = {a00, a01, a02, a03}, r1v[4] = {a10, a11, a12, a13};
#pragma unroll
      for (int j = 0; j < 4; j++) {
        if (c0 + j < HIDN) {
          float bb = b1[c0 + j];
          hm[row0 * 80 + c0 + j] = tanhf(r0v[j] + bb);
          hm[(row0 + 1) * 80 + c0 + j] = tanhf(r1v[j] + bb);
        }
      }
    }
  }
  __syncthreads();

  // phase 2: x_rec = tanh(hm @ w2 + b2); xs = x + x_rec; recT for out_rec
  {
    float a00 = 0, a01 = 0, a02 = 0, a03 = 0, a10 = 0, a11 = 0, a12 = 0, a13 = 0;
    const float* H0 = hm + row0 * 80;
    const float* H1 = H0 + 80;
#pragma unroll 4
    for (int k = 0; k < HIDN; k++) {
      float4 wv = *(const float4*)&W2s[k * 128 + c0];
      float a0 = H0[k], a1 = H1[k];
      a00 += a0 * wv.x; a01 += a0 * wv.y; a02 += a0 * wv.z; a03 += a0 * wv.w;
      a10 += a1 * wv.x; a11 += a1 * wv.y; a12 += a1 * wv.z; a13 += a1 * wv.w;
    }
    float4 bv = *(const float4*)&b2[c0];
    float x00 = tanhf(a00 + bv.x), x01 = tanhf(a01 + bv.y), x02 = tanhf(a02 + bv.z), x03 = tanhf(a03 + bv.w);
    float x10 = tanhf(a10 + bv.x), x11 = tanhf(a11 + bv.y), x12 = tanhf(a12 + bv.z), x13 = tanhf(a13 + bv.w);
    const float* X0 = xbt + row0 * 132;
    const float* X1 = X0 + 132;
    float4 s0 = make_float4(X0[c0] + x00, X0[c0 + 1] + x01, X0[c0 + 2] + x02, X0[c0 + 3] + x03);
    float4 s1 = make_float4(X1[c0] + x10, X1[c0 + 1] + x11, X1[c0 + 2] + x12, X1[c0 + 3] + x13);
    *(float4*)&xs[(size_t)(r0 + row0) * 128 + c0] = s0;
    *(float4*)&xs[(size_t)(r0 + row0 + 1) * 128 + c0] = s1;
    recT[(c0 + 0) * 17 + row0] = x00; recT[(c0 + 1) * 17 + row0] = x01;
    recT[(c0 + 2) * 17 + row0] = x02; recT[(c0 + 3) * 17 + row0] = x03;
    recT[(c0 + 0) * 17 + row0 + 1] = x10; recT[(c0 + 1) * 17 + row0 + 1] = x11;
    recT[(c0 + 2) * 17 + row0 + 1] = x12; recT[(c0 + 3) * 17 + row0 + 1] = x13;
  }
  __syncthreads();
  float* orc = out_rec + (size_t)b * 8192 + n0;
  for (int t = tid; t < 2048; t += 256) {
    int w = t >> 4, i = t & 15;
    orc[w * 64 + i] = recT[w * 17 + i];
  }
}

// ---------------- K3: left/right projections (ta_b folded into left) ----------------
__global__ __launch_bounds__(256) void k_lr(const float* __restrict__ xs, const float* __restrict__ ta_w,
                                            const float* __restrict__ ta_b, float* __restrict__ leftT,
                                            float* __restrict__ rightT) {
  int wave = threadIdx.x >> 6, lane = threadIdx.x & 63;
  int idx = blockIdx.x * 4 + wave;
  int b = idx >> 7, e = idx & 127;
  int c = lane * 2;
  const float* xsb = xs + (size_t)b * 8192;
  float lx = 0, ly = 0, rx = 0, ry = 0;
#pragma unroll 4
  for (int n = 0; n < 64; n++) {
    float wl = ta_w[n * 128 + e];
    float wr = ta_w[(64 + n) * 128 + e];
    float2 xv = *(const float2*)&xsb[n * 128 + c];
    lx += wl * xv.x; ly += wl * xv.y;
    rx += wr * xv.x; ry += wr * xv.y;
  }
  float tb = ta_b[e];
  *(float2*)&leftT[((size_t)b * 128 + e) * 128 + c] = make_float2(lx + tb, ly + tb);
  *(float2*)&rightT[((size_t)b * 128 + e) * 128 + c] = make_float2(rx, ry);
}

// ---------------- K4: fused e-score (|t| form) + softmax + PV + tanh -> ht ----------------
__global__ __launch_bounds__(512) void k_attn(const float* __restrict__ LEFT_, const float* __restrict__ RIGHT_,
                                              const float* __restrict__ ta_a, const float* __restrict__ ta_bias,
                                              const float* __restrict__ xs, float* __restrict__ ht) {
  __shared__ float Rf[128 * 128];   // 64 KB
  __shared__ float Lh[32 * 132];    // e-phase [128][32]; reused as P[32][132]
  __shared__ float xsT[128 * 68];   // 34 KB
  __shared__ float av2[128], av6[128], uu[32], vv[128];
  int tid = threadIdx.x;
  int b = blockIdx.x >> 2, q = blockIdx.x & 3;
  int i0 = q * 32;

  {
    const float4* R4 = (const float4*)(RIGHT_ + (size_t)b * 16384);
    float4* Rf4 = (float4*)Rf;
#pragma unroll
    for (int t = 0; t < 8; t++) Rf4[tid + t * 512] = R4[tid + t * 512];
  }
  {
    const float* Lp = LEFT_ + (size_t)b * 16384 + i0;
#pragma unroll
    for (int t = 0; t < 8; t++) {
      int idx = tid + t * 512;
      Lh[idx] = Lp[(idx >> 5) * 128 + (idx & 31)];
    }
  }
  {
    const float* xsb = xs + (size_t)b * 8192;
#pragma unroll
    for (int t = 0; t < 16; t++) {
      int idx = tid + t * 512;
      xsT[(idx & 127) * 68 + (idx >> 7)] = xsb[idx];
    }
  }
  if (tid < 128) { float a = ta_a[tid]; av2[tid] = 0.4f * a; av6[tid] = 0.6f * a; }
  __syncthreads();

  // rank-1 parts: u_i = 0.6*sum_e a_e L[e][i], v_j = 0.6*sum_e a_e R[e][j]
  if (tid < 160) {
    float acc = 0.f;
    if (tid < 128) {
      for (int e = 0; e < 128; e++) acc += av6[e] * Rf[e * 128 + tid];
      vv[tid] = acc;
    } else {
      int i = tid - 128;
      for (int e = 0; e < 128; e++) acc += av6[e] * Lh[e * 32 + i];
      uu[i] = acc;
    }
  }
  __syncthreads();

  int tj = tid & 31, ti = tid >> 5;  // ti 0..15 -> 2 i rows each
  float acc[2][4];
#pragma unroll
  for (int a = 0; a < 2; a++)
#pragma unroll
    for (int j = 0; j < 4; j++) acc[a][j] = 0.f;

#pragma unroll 2
  for (int e = 0; e < 128; e++) {
    float2 L = *(const float2*)&Lh[e * 32 + ti * 2];
    float4 R = *(const float4*)&Rf[e * 128 + tj * 4];
    float ae = av2[e];
    float Ra[4] = {R.x, R.y, R.z, R.w};
    float La[2] = {L.x, L.y};
#pragma unroll
    for (int a = 0; a < 2; a++)
#pragma unroll
      for (int j = 0; j < 4; j++) {
        float t = La[a] + Ra[j];
        acc[a][j] += ae * fabsf(t);   // abs is free VOP3 modifier
      }
  }

  // epilogue: + 0.6(u+v) + bias, then row softmax over the 32-lane half-wave
  float p[2][4];
#pragma unroll
  for (int a = 0; a < 2; a++) {
    int i = i0 + ti * 2 + a;
    float uvi = uu[ti * 2 + a];
    float4 bv = *(const float4*)&ta_bias[(size_t)i * 128 + tj * 4];
    float v0 = acc[a][0] + bv.x + uvi + vv[tj * 4 + 0];
    float v1 = acc[a][1] + bv.y + uvi + vv[tj * 4 + 1];
    float v2 = acc[a][2] + bv.z + uvi + vv[tj * 4 + 2];
    float v3 = acc[a][3] + bv.w + uvi + vv[tj * 4 + 3];
    float m = fmaxf(fmaxf(v0, v1), fmaxf(v2, v3));
#pragma unroll
    for (int o = 16; o > 0; o >>= 1) m = fmaxf(m, __shfl_xor(m, o));
    float e0 = __expf(v0 - m), e1 = __expf(v1 - m), e2 = __expf(v2 - m), e3 = __expf(v3 - m);
    float s = e0 + e1 + e2 + e3;
#pragma unroll
    for (int o = 16; o > 0; o >>= 1) s += __shfl_xor(s, o);
    float inv = 1.f / s;
    p[a][0] = e0 * inv; p[a][1] = e1 * inv; p[a][2] = e2 * inv; p[a][3] = e3 * inv;
  }
  __syncthreads();
  float* P = Lh;  // [32][132]
  *(float4*)&P[(ti * 2 + 0) * 132 + tj * 4] = make_float4(p[0][0], p[0][1], p[0][2], p[0][3]);
  *(float4*)&P[(ti * 2 + 1) * 132 + tj * 4] = make_float4(p[1][0], p[1][1], p[1][2], p[1][3]);
  __syncthreads();

  // PV: ht[i][n] = sum_j P[i][j] * xsT[j][n]
  int tn = tid & 15, i2 = tid >> 4;
  float o0 = 0, o1 = 0, o2 = 0, o3 = 0;
  const float* Prow = P + i2 * 132;
#pragma unroll 4
  for (int j = 0; j < 128; j++) {
    float4 xv = *(const float4*)&xsT[j * 68 + tn * 4];
    float pv = Prow[j];
    o0 += pv * xv.x; o1 += pv * xv.y; o2 += pv * xv.z; o3 += pv * xv.w;
  }
  float* hto = ht + (size_t)b * 8192 + (size_t)(i0 + i2) * 64 + tn * 4;
  *(float4*)hto = make_float4(tanhf(o0), tanhf(o1), tanhf(o2), tanhf(o3));
}

// ---------------- K5: fused GAT: GEMM + edge-softmax aggregate + FC + tanh (block = batch) ----------------
__global__ __launch_bounds__(512) void k_gat(const float* __restrict__ ht, const float* __restrict__ gw,
                                             const float* __restrict__ asrc, const float* __restrict__ adst,
                                             const float* __restrict__ gb, const float* __restrict__ fcw,
                                             const float* __restrict__ fcb,
                                             const int* __restrict__ off, const int* __restrict__ list,
                                             float* __restrict__ outp) {
  __shared__ float Ws[128 * 128];   // 64 KB
  __shared__ float AsT[64 * 132];   // 33 KB
  __shared__ float H2[64 * 132];    // 33 KB (pad 132 -> no 8-way bank aliasing on gather)
  __shared__ float ss_s[64], sd_s[64];
  __shared__ int offs_s[65];
  __shared__ int list_s[1408];
  int tid = threadIdx.x, b = blockIdx.x;
  {
    const float4* W4 = (const float4*)gw;
    float4* Ws4 = (float4*)Ws;
    for (int t = tid; t < 4096; t += 512) Ws4[t] = W4[t];
  }
  const float* hb = ht + (size_t)b * 8192;
  for (int t = tid; t < 8192; t += 512) {
    int k = t >> 6, n = t & 63;
    AsT[n * 132 + k] = hb[t];
  }
  if (tid < 65) offs_s[tid] = off[tid];
  __syncthreads();
  int totE = offs_s[64];
  for (int t = tid; t < totE; t += 512) list_s[t] = list[t];
  // no barrier needed yet for list_s (used after next one)

  int tx = tid & 31, ty = tid >> 5;  // ty 0..15 -> 4 rows each
  int c0 = tx * 4, row0 = ty * 4;
  float acc[4][4];
#pragma unroll
  for (int r = 0; r < 4; r++)
#pragma unroll
    for (int j = 0; j < 4; j++) acc[r][j] = 0.f;
#pragma unroll 2
  for (int k = 0; k < 128; k++) {
    float4 wv = *(const float4*)&Ws[k * 128 + c0];
#pragma unroll
    for (int r = 0; r < 4; r++) {
      float a = AsT[(row0 + r) * 132 + k];
      acc[r][0] += a * wv.x; acc[r][1] += a * wv.y; acc[r][2] += a * wv.z; acc[r][3] += a * wv.w;
    }
  }
  float4 as4 = *(const float4*)&asrc[c0];
  float4 ad4 = *(const float4*)&adst[c0];
#pragma unroll
  for (int r = 0; r < 4; r++) {
    *(float4*)&H2[(row0 + r) * 132 + c0] = make_float4(acc[r][0], acc[r][1], acc[r][2], acc[r][3]);
    float ss = acc[r][0] * as4.x + acc[r][1] * as4.y + acc[r][2] * as4.z + acc[r][3] * as4.w;
    float sd = acc[r][0] * ad4.x + acc[r][1] * ad4.y + acc[r][2] * ad4.z + acc[r][3] * ad4.w;
#pragma unroll
    for (int m = 16; m > 0; m >>= 1) { ss += __shfl_xor(ss, m); sd += __shfl_xor(sd, m); }
    if (tx == 0) { ss_s[row0 + r] = ss; sd_s[row0 + r] = sd; }
  }
  __syncthreads();

  // edge softmax + aggregate: thread = 1 row x 16 cols
  int row = tid >> 3, tc = tid & 7;
  int cb = tc * 16;
  int e0 = offs_s[row], e1 = offs_s[row + 1];
  float sdv = sd_s[row];
  float mx = -1e30f;
  for (int e = e0; e < e1; e++) {
    float t = ss_s[list_s[e]] + sdv;
    t = fmaxf(t, 0.2f * t);
    mx = fmaxf(mx, t);
  }
  float den = 0.f;
  float o[16];
#pragma unroll
  for (int j = 0; j < 16; j++) o[j] = 0.f;
  for (int e = e0; e < e1; e++) {
    int s = list_s[e];
    float t = ss_s[s] + sdv;
    t = fmaxf(t, 0.2f * t);
    float w = __expf(t - mx);
    den += w;
    const float* hp = &H2[s * 132 + cb];
    float4 h0 = *(const float4*)hp;
    float4 h1 = *(const float4*)(hp + 4);
    float4 h2v = *(const float4*)(hp + 8);
    float4 h3 = *(const float4*)(hp + 12);
    o[0] += w * h0.x;  o[1] += w * h0.y;  o[2] += w * h0.z;  o[3] += w * h0.w;
    o[4] += w * h1.x;  o[5] += w * h1.y;  o[6] += w * h1.z;  o[7] += w * h1.w;
    o[8] += w * h2v.x; o[9] += w * h2v.y; o[10] += w * h2v.z; o[11] += w * h2v.w;
    o[12] += w * h3.x; o[13] += w * h3.y; o[14] += w * h3.z; o[15] += w * h3.w;
  }
  float inv = 1.f / den;
  float xp = 0.f;
#pragma unroll
  for (int j = 0; j < 16; j++) xp += (o[j] * inv + gb[cb + j]) * fcw[cb + j];
#pragma unroll
  for (int m = 4; m > 0; m >>= 1) xp += __shfl_xor(xp, m);
  if (tc == 0) outp[b * 64 + row] = tanhf(xp + fcb[0]);
}

extern "C" void kernel_launch(void* const* d_in, const int* in_sizes, int n_in,
                              void* d_out, int out_size, void* d_ws, size_t ws_size,
                              hipStream_t stream) {
  (void)n_in; (void)out_size; (void)ws_size;
  const float* x        = (const float*)d_in[0];
  const float* gl_embed = (const float*)d_in[7];
  const float* gcn_w    = (const float*)d_in[8];
  const float* gcn_b    = (const float*)d_in[9];
  const float* mlp_w1   = (const float*)d_in[10];
  const float* mlp_b1   = (const float*)d_in[11];
  const float* mlp_w2   = (const float*)d_in[12];
  const float* mlp_b2   = (const float*)d_in[13];
  const float* ta_w     = (const float*)d_in[14];
  const float* ta_b     = (const float*)d_in[15];
  const float* ta_a     = (const float*)d_in[16];
  const float* ta_bias  = (const float*)d_in[17];
  const float* gat_w    = (const float*)d_in[18];
  const float* gat_asrc = (const float*)d_in[19];
  const float* gat_adst = (const float*)d_in[20];
  const float* gat_b    = (const float*)d_in[21];
  const float* fc_w     = (const float*)d_in[22];
  const float* fc_b     = (const float*)d_in[23];
  const int*   gat_ei   = (const int*)d_in[24];
  const int*   gl_ei    = (const int*)d_in[25];

  int E_gat = in_sizes[24] / (2 * BB);  // 1280
  int E_gl  = in_sizes[25] / (2 * BB);  // 1638

  float* ws = (float*)d_ws;
  float* HRAW  = ws + 0;        // 524288
  float* XS    = ws + 524288;   // 524288
  float* LEFT  = ws + 1048576;  // 1048576
  float* RIGHT = ws + 2097152;  // 1048576
  float* HT    = ws + 3145728;  // 524288
  float* COEF  = ws + 3670016;  // 2048
  int*   IP    = (int*)(ws + 3672064);
  int* GLOFF   = IP;            // 72
  int* GLLIST  = IP + 72;       // 2048
  int* GATOFF  = IP + 2120;     // 72
  int* GATLIST = IP + 2192;     // 2048

  float* out_rec = (float*)d_out;
  float* out_pre = (float*)d_out + 524288;

  k_gemm_csr<<<256, 256, 0, stream>>>(x, gl_embed, gcn_w, gl_ei, E_gl, gat_ei, E_gat,
                                      HRAW, GLOFF, GLLIST, COEF, GATOFF, GATLIST);
  k_aggmlp<<<256, 256, 0, stream>>>(HRAW, GLOFF, GLLIST, COEF, gcn_b, mlp_w1, mlp_b1,
                                    mlp_w2, mlp_b2, x, XS, out_rec);
  k_lr<<<2048, 256, 0, stream>>>(XS, ta_w, ta_b, LEFT, RIGHT);
  k_attn<<<256, 512, 0, stream>>>(LEFT, RIGHT, ta_a, ta_bias, XS, HT);
  k_gat<<<64, 512, 0, stream>>>(HT, gat_w, gat_asrc, gat_adst, gat_b, fc_w, fc_b,
                                GATOFF, GATLIST, out_pre);
}

// Round 4
// 118.337 us; speedup vs baseline: 1.7703x; 1.0423x over previous
//
#include <hip/hip_runtime.h>
#include <math.h>

#define BB  64
#define WW  128
#define NN  64
#define HIDN 77

// ---------------- K1: GCN as dense: hA = relu((S @ [x|emb]) @ gcn_w + b) ----------------
// S (64x64, incl self-loops + sym-norm coefs) built per block from the edge list.
// Block 255 additionally builds the GAT CSR (LDS reused after main work).
__global__ __launch_bounds__(256) void k_gcn(const float* __restrict__ x, const float* __restrict__ emb,
                                             const float* __restrict__ wg, const float* __restrict__ gcn_b,
                                             const int* __restrict__ gl_ei, int E_gl,
                                             const int* __restrict__ gat_ei, int E_gat,
                                             float* __restrict__ hA,
                                             int* __restrict__ gat_off, int* __restrict__ gat_list) {
  __shared__ float Ws[140 * 128];    // 71680 B
  __shared__ float xn[128 * 68];     // 34816 B  x[b] natural [w][n] pad 68
  __shared__ float Sm[16 * 68];      // 4352 B   S rows for this block's 16 dst
  __shared__ float XA[16 * 144];     // 9216 B   aggregated tile, cols 0..139
  __shared__ float embs[64 * 12];    // 3072 B
  __shared__ float gbb[128];
  __shared__ float dinv[64];
  __shared__ int cnt[64];
  int tid = threadIdx.x;
  int r0 = blockIdx.x * 16;
  int b = r0 >> 6, n0 = r0 & 63;

  {
    const float4* W4 = (const float4*)wg;
    float4* Ws4 = (float4*)Ws;
    for (int t = tid; t < 4480; t += 256) Ws4[t] = W4[t];
  }
  {
    const float4* x4 = (const float4*)(x + (size_t)b * 8192);
    for (int t = tid; t < 2048; t += 256) {
      int w = t >> 4, nq = t & 15;
      *(float4*)&xn[w * 68 + nq * 4] = x4[t];
    }
  }
  if (tid < 192) {
    embs[tid] = emb[tid]; embs[tid + 192] = emb[tid + 192];
    embs[tid + 384] = emb[tid + 384]; embs[tid + 576] = emb[tid + 576];
  }
  if (tid < 128) gbb[tid] = gcn_b[tid];
  if (tid < 64) cnt[tid] = 1;  // self-loop
  for (int t = tid; t < 1088; t += 256) Sm[t] = 0.f;
  __syncthreads();
  // scan 1: degrees (dst counts)
  for (int e = tid; e < E_gl; e += 256) atomicAdd(&cnt[gl_ei[BB * E_gl + e]], 1);
  __syncthreads();
  if (tid < 64) dinv[tid] = rsqrtf((float)cnt[tid]);
  __syncthreads();
  // scan 2: fill S rows owned by this block
  for (int e = tid; e < E_gl; e += 256) {
    int dst = gl_ei[BB * E_gl + e];
    int d = dst - n0;
    if ((unsigned)d < 16u) {
      int src = gl_ei[e];
      Sm[d * 68 + src] = dinv[src] * dinv[dst];
    }
  }
  __syncthreads();
  if (tid < 16) {
    int n = n0 + tid;
    Sm[tid * 68 + n] += dinv[n] * dinv[n];
  }
  __syncthreads();
  // aggregate: XA[i][w] = sum_s Sm[i][s] * xn[w][s]
  {
    int i = tid >> 4, tw = tid & 15;
    float o[8] = {0, 0, 0, 0, 0, 0, 0, 0};
    for (int s4 = 0; s4 < 16; s4++) {
      float4 sv = *(const float4*)&Sm[i * 68 + s4 * 4];
#pragma unroll
      for (int r = 0; r < 8; r++) {
        float4 xv = *(const float4*)&xn[(tw + 16 * r) * 68 + s4 * 4];
        o[r] += sv.x * xv.x + sv.y * xv.y + sv.z * xv.z + sv.w * xv.w;
      }
    }
#pragma unroll
    for (int r = 0; r < 8; r++) XA[i * 144 + tw + 16 * r] = o[r];
  }
  if (tid < 192) {
    int i = tid / 12, j = tid % 12;
    float acc = 0.f;
    for (int s = 0; s < 64; s++) acc += Sm[i * 68 + s] * embs[s * 12 + j];
    XA[i * 144 + 128 + j] = acc;
  }
  __syncthreads();
  // GEMM: 16 x 140 @ 140 x 128 (+bias, relu)
  {
    int tx = tid & 31, ty = tid >> 5;
    int row0 = ty * 2, c0 = tx * 4;
    float a00 = 0, a01 = 0, a02 = 0, a03 = 0, a10 = 0, a11 = 0, a12 = 0, a13 = 0;
    const float* A0 = XA + row0 * 144;
    const float* A1 = A0 + 144;
#pragma unroll 4
    for (int k = 0; k < 140; k++) {
      float4 wv = *(const float4*)&Ws[k * 128 + c0];
      float a0 = A0[k], a1 = A1[k];
      a00 += a0 * wv.x; a01 += a0 * wv.y; a02 += a0 * wv.z; a03 += a0 * wv.w;
      a10 += a1 * wv.x; a11 += a1 * wv.y; a12 += a1 * wv.z; a13 += a1 * wv.w;
    }
    float4 bv = *(const float4*)&gbb[c0];
    float* o = hA + (size_t)(r0 + row0) * 128 + c0;
    *(float4*)o = make_float4(fmaxf(a00 + bv.x, 0.f), fmaxf(a01 + bv.y, 0.f),
                              fmaxf(a02 + bv.z, 0.f), fmaxf(a03 + bv.w, 0.f));
    *(float4*)(o + 128) = make_float4(fmaxf(a10 + bv.x, 0.f), fmaxf(a11 + bv.y, 0.f),
                                      fmaxf(a12 + bv.z, 0.f), fmaxf(a13 + bv.w, 0.f));
  }

  // ---- block 255 tail: build GAT CSR once ----
  if (blockIdx.x == 255) {
    __syncthreads();
    int* offs = (int*)Sm;        // 65 ints
    int* cur  = offs + 65;       // 64 ints (fits in Sm's 1088 floats)
    int* lst  = (int*)XA;        // 2304 ints >= 1344
    if (tid < 64) cnt[tid] = 1;
    __syncthreads();
    for (int e = tid; e < E_gat; e += 256) atomicAdd(&cnt[gat_ei[BB * E_gat + e]], 1);
    __syncthreads();
    if (tid == 0) { int s = 0; for (int n = 0; n < 64; n++) { offs[n] = s; s += cnt[n]; } offs[64] = s; }
    __syncthreads();
    if (tid < 64) cur[tid] = offs[tid];
    __syncthreads();
    for (int e = tid; e < E_gat; e += 256) {
      int src = gat_ei[e], dst = gat_ei[BB * E_gat + e];
      lst[atomicAdd(&cur[dst], 1)] = src;
    }
    if (tid < 64) lst[atomicAdd(&cur[tid], 1)] = tid;
    __syncthreads();
    if (tid < 65) gat_off[tid] = offs[tid];
    int tot = offs[64];
    for (int t = tid; t < tot; t += 256) gat_list[t] = lst[t];
  }
}

// ---------------- K2: MLP: hA -> hmid -> x_rec -> xs, out_rec (70 KB LDS, 2 blocks/CU) ----------------
__global__ __launch_bounds__(256) void k_mlp(const float* __restrict__ hA, const float* __restrict__ w1,
                                             const float* __restrict__ b1, const float* __restrict__ w2,
                                             const float* __restrict__ b2, const float* __restrict__ x,
                                             float* __restrict__ xs, float* __restrict__ out_rec) {
  __shared__ float Wbuf[10240];     // W1 [128][80] then W2 [77][128]
  __shared__ float As1[16 * 132];
  __shared__ float hm[16 * 80];
  __shared__ float xbt[16 * 132];
  __shared__ float recT[128 * 17];
  int tid = threadIdx.x;
  int r0 = blockIdx.x * 16;
  int b = r0 >> 6, n0 = r0 & 63;

  {
    const float4* h4 = (const float4*)(hA + (size_t)r0 * 128);
    for (int t = tid; t < 512; t += 256) {
      int row = t >> 5, q = t & 31;
      *(float4*)&As1[row * 132 + q * 4] = h4[t];
    }
  }
  for (int t = tid; t < 10240; t += 256) {
    int k = t / 80, c = t % 80;
    Wbuf[t] = (c < HIDN) ? w1[k * HIDN + c] : 0.f;
  }
  const float* xb = x + (size_t)b * 8192 + n0;
  for (int t = tid; t < 2048; t += 256) {
    int w = t >> 4, i = t & 15;
    xbt[i * 132 + w] = xb[w * 64 + i];
  }
  __syncthreads();

  int tx = tid & 31, ty = tid >> 5;
  int row0 = ty * 2;
  int c0 = tx * 4;
  bool act = c0 < HIDN;
  int cW = act ? c0 : 0;

  // phase 1: hm = tanh(As1 @ W1 + b1)
  {
    float a00 = 0, a01 = 0, a02 = 0, a03 = 0, a10 = 0, a11 = 0, a12 = 0, a13 = 0;
    const float* A0 = As1 + row0 * 132;
    const float* A1 = A0 + 132;
#pragma unroll 4
    for (int k = 0; k < 128; k++) {
      float4 wv = *(const float4*)&Wbuf[k * 80 + cW];
      float a0 = A0[k], a1 = A1[k];
      a00 += a0 * wv.x; a01 += a0 * wv.y; a02 += a0 * wv.z; a03 += a0 * wv.w;
      a10 += a1 * wv.x; a11 += a1 * wv.y; a12 += a1 * wv.z; a13 += a1 * wv.w;
    }
    if (act) {
      float r0v[4] = {a00, a01, a02, a03}, r1v[4] = {a10, a11, a12, a13};
#pragma unroll
      for (int j = 0; j < 4; j++) {
        if (c0 + j < HIDN) {
          float bb = b1[c0 + j];
          hm[row0 * 80 + c0 + j] = tanhf(r0v[j] + bb);
          hm[(row0 + 1) * 80 + c0 + j] = tanhf(r1v[j] + bb);
        }
      }
    }
  }
  __syncthreads();
  // stage W2 into Wbuf
  {
    const float4* w24 = (const float4*)w2;
    float4* Wb4 = (float4*)Wbuf;
    for (int t = tid; t < 2464; t += 256) Wb4[t] = w24[t];
  }
  __syncthreads();

  // phase 2: x_rec = tanh(hm @ W2 + b2); xs = x + x_rec
  {
    float a00 = 0, a01 = 0, a02 = 0, a03 = 0, a10 = 0, a11 = 0, a12 = 0, a13 = 0;
    const float* H0 = hm + row0 * 80;
    const float* H1 = H0 + 80;
#pragma unroll 4
    for (int k = 0; k < HIDN; k++) {
      float4 wv = *(const float4*)&Wbuf[k * 128 + c0];
      float a0 = H0[k], a1 = H1[k];
      a00 += a0 * wv.x; a01 += a0 * wv.y; a02 += a0 * wv.z; a03 += a0 * wv.w;
      a10 += a1 * wv.x; a11 += a1 * wv.y; a12 += a1 * wv.z; a13 += a1 * wv.w;
    }
    float4 bv = *(const float4*)&b2[c0];
    float x00 = tanhf(a00 + bv.x), x01 = tanhf(a01 + bv.y), x02 = tanhf(a02 + bv.z), x03 = tanhf(a03 + bv.w);
    float x10 = tanhf(a10 + bv.x), x11 = tanhf(a11 + bv.y), x12 = tanhf(a12 + bv.z), x13 = tanhf(a13 + bv.w);
    const float* X0 = xbt + row0 * 132;
    const float* X1 = X0 + 132;
    *(float4*)&xs[(size_t)(r0 + row0) * 128 + c0] =
        make_float4(X0[c0] + x00, X0[c0 + 1] + x01, X0[c0 + 2] + x02, X0[c0 + 3] + x03);
    *(float4*)&xs[(size_t)(r0 + row0 + 1) * 128 + c0] =
        make_float4(X1[c0] + x10, X1[c0 + 1] + x11, X1[c0 + 2] + x12, X1[c0 + 3] + x13);
    recT[(c0 + 0) * 17 + row0] = x00; recT[(c0 + 1) * 17 + row0] = x01;
    recT[(c0 + 2) * 17 + row0] = x02; recT[(c0 + 3) * 17 + row0] = x03;
    recT[(c0 + 0) * 17 + row0 + 1] = x10; recT[(c0 + 1) * 17 + row0 + 1] = x11;
    recT[(c0 + 2) * 17 + row0 + 1] = x12; recT[(c0 + 3) * 17 + row0 + 1] = x13;
  }
  __syncthreads();
  float* orc = out_rec + (size_t)b * 8192 + n0;
  for (int t = tid; t < 2048; t += 256) {
    int w = t >> 4, i = t & 15;
    orc[w * 64 + i] = recT[w * 17 + i];
  }
}

// ---------------- K3: left/right projections (ta_b folded into left) ----------------
__global__ __launch_bounds__(256) void k_lr(const float* __restrict__ xs, const float* __restrict__ ta_w,
                                            const float* __restrict__ ta_b, float* __restrict__ leftT,
                                            float* __restrict__ rightT) {
  int wave = threadIdx.x >> 6, lane = threadIdx.x & 63;
  int idx = blockIdx.x * 4 + wave;
  int b = idx >> 7, e = idx & 127;
  int c = lane * 2;
  const float* xsb = xs + (size_t)b * 8192;
  float lx = 0, ly = 0, rx = 0, ry = 0;
#pragma unroll 4
  for (int n = 0; n < 64; n++) {
    float wl = ta_w[n * 128 + e];
    float wr = ta_w[(64 + n) * 128 + e];
    float2 xv = *(const float2*)&xsb[n * 128 + c];
    lx += wl * xv.x; ly += wl * xv.y;
    rx += wr * xv.x; ry += wr * xv.y;
  }
  float tb = ta_b[e];
  *(float2*)&leftT[((size_t)b * 128 + e) * 128 + c] = make_float2(lx + tb, ly + tb);
  *(float2*)&rightT[((size_t)b * 128 + e) * 128 + c] = make_float2(rx, ry);
}

// ---------------- K4: fused e-score (|t| form) + softmax + PV + tanh -> ht ----------------
__global__ __launch_bounds__(512) void k_attn(const float* __restrict__ LEFT_, const float* __restrict__ RIGHT_,
                                              const float* __restrict__ ta_a, const float* __restrict__ ta_bias,
                                              const float* __restrict__ xs, float* __restrict__ ht) {
  __shared__ float Rf[128 * 128];
  __shared__ float Lh[32 * 132];
  __shared__ float xsT[128 * 68];
  __shared__ float av2[128], av6[128], uu[32], vv[128];
  int tid = threadIdx.x;
  int b = blockIdx.x >> 2, q = blockIdx.x & 3;
  int i0 = q * 32;

  {
    const float4* R4 = (const float4*)(RIGHT_ + (size_t)b * 16384);
    float4* Rf4 = (float4*)Rf;
#pragma unroll
    for (int t = 0; t < 8; t++) Rf4[tid + t * 512] = R4[tid + t * 512];
  }
  {
    const float* Lp = LEFT_ + (size_t)b * 16384 + i0;
#pragma unroll
    for (int t = 0; t < 8; t++) {
      int idx = tid + t * 512;
      Lh[idx] = Lp[(idx >> 5) * 128 + (idx & 31)];
    }
  }
  {
    const float* xsb = xs + (size_t)b * 8192;
#pragma unroll
    for (int t = 0; t < 16; t++) {
      int idx = tid + t * 512;
      xsT[(idx & 127) * 68 + (idx >> 7)] = xsb[idx];
    }
  }
  if (tid < 128) { float a = ta_a[tid]; av2[tid] = 0.4f * a; av6[tid] = 0.6f * a; }
  __syncthreads();

  if (tid < 160) {
    float acc = 0.f;
    if (tid < 128) {
      for (int e = 0; e < 128; e++) acc += av6[e] * Rf[e * 128 + tid];
      vv[tid] = acc;
    } else {
      int i = tid - 128;
      for (int e = 0; e < 128; e++) acc += av6[e] * Lh[e * 32 + i];
      uu[i] = acc;
    }
  }
  __syncthreads();

  int tj = tid & 31, ti = tid >> 5;
  float acc[2][4];
#pragma unroll
  for (int a = 0; a < 2; a++)
#pragma unroll
    for (int j = 0; j < 4; j++) acc[a][j] = 0.f;

#pragma unroll 2
  for (int e = 0; e < 128; e++) {
    float2 L = *(const float2*)&Lh[e * 32 + ti * 2];
    float4 R = *(const float4*)&Rf[e * 128 + tj * 4];
    float ae = av2[e];
    float Ra[4] = {R.x, R.y, R.z, R.w};
    float La[2] = {L.x, L.y};
#pragma unroll
    for (int a = 0; a < 2; a++)
#pragma unroll
      for (int j = 0; j < 4; j++) {
        float t = La[a] + Ra[j];
        acc[a][j] += ae * fabsf(t);
      }
  }

  float p[2][4];
#pragma unroll
  for (int a = 0; a < 2; a++) {
    int i = i0 + ti * 2 + a;
    float uvi = uu[ti * 2 + a];
    float4 bv = *(const float4*)&ta_bias[(size_t)i * 128 + tj * 4];
    float v0 = acc[a][0] + bv.x + uvi + vv[tj * 4 + 0];
    float v1 = acc[a][1] + bv.y + uvi + vv[tj * 4 + 1];
    float v2 = acc[a][2] + bv.z + uvi + vv[tj * 4 + 2];
    float v3 = acc[a][3] + bv.w + uvi + vv[tj * 4 + 3];
    float m = fmaxf(fmaxf(v0, v1), fmaxf(v2, v3));
#pragma unroll
    for (int o = 16; o > 0; o >>= 1) m = fmaxf(m, __shfl_xor(m, o));
    float e0 = __expf(v0 - m), e1 = __expf(v1 - m), e2 = __expf(v2 - m), e3 = __expf(v3 - m);
    float s = e0 + e1 + e2 + e3;
#pragma unroll
    for (int o = 16; o > 0; o >>= 1) s += __shfl_xor(s, o);
    float inv = 1.f / s;
    p[a][0] = e0 * inv; p[a][1] = e1 * inv; p[a][2] = e2 * inv; p[a][3] = e3 * inv;
  }
  __syncthreads();
  float* P = Lh;
  *(float4*)&P[(ti * 2 + 0) * 132 + tj * 4] = make_float4(p[0][0], p[0][1], p[0][2], p[0][3]);
  *(float4*)&P[(ti * 2 + 1) * 132 + tj * 4] = make_float4(p[1][0], p[1][1], p[1][2], p[1][3]);
  __syncthreads();

  int tn = tid & 15, i2 = tid >> 4;
  float o0 = 0, o1 = 0, o2 = 0, o3 = 0;
  const float* Prow = P + i2 * 132;
#pragma unroll 4
  for (int j = 0; j < 128; j++) {
    float4 xv = *(const float4*)&xsT[j * 68 + tn * 4];
    float pv = Prow[j];
    o0 += pv * xv.x; o1 += pv * xv.y; o2 += pv * xv.z; o3 += pv * xv.w;
  }
  float* hto = ht + (size_t)b * 8192 + (size_t)(i0 + i2) * 64 + tn * 4;
  *(float4*)hto = make_float4(tanhf(o0), tanhf(o1), tanhf(o2), tanhf(o3));
}

// ---------------- K5: fused GAT: GEMM + edge-softmax aggregate + FC + tanh (block = batch) ----------------
__global__ __launch_bounds__(512) void k_gat(const float* __restrict__ ht, const float* __restrict__ gw,
                                             const float* __restrict__ asrc, const float* __restrict__ adst,
                                             const float* __restrict__ gb, const float* __restrict__ fcw,
                                             const float* __restrict__ fcb,
                                             const int* __restrict__ off, const int* __restrict__ list,
                                             float* __restrict__ outp) {
  __shared__ float Ws[128 * 128];
  __shared__ float AsT[64 * 132];
  __shared__ float H2[64 * 132];
  __shared__ float ss_s[64], sd_s[64];
  __shared__ int offs_s[65];
  __shared__ int list_s[1408];
  int tid = threadIdx.x, b = blockIdx.x;
  {
    const float4* W4 = (const float4*)gw;
    float4* Ws4 = (float4*)Ws;
    for (int t = tid; t < 4096; t += 512) Ws4[t] = W4[t];
  }
  const float* hb = ht + (size_t)b * 8192;
  for (int t = tid; t < 8192; t += 512) {
    int k = t >> 6, n = t & 63;
    AsT[n * 132 + k] = hb[t];
  }
  if (tid < 65) offs_s[tid] = off[tid];
  __syncthreads();
  int totE = offs_s[64];
  for (int t = tid; t < totE; t += 512) list_s[t] = list[t];

  int tx = tid & 31, ty = tid >> 5;
  int c0 = tx * 4, row0 = ty * 4;
  float acc[4][4];
#pragma unroll
  for (int r = 0; r < 4; r++)
#pragma unroll
    for (int j = 0; j < 4; j++) acc[r][j] = 0.f;
#pragma unroll 2
  for (int k = 0; k < 128; k++) {
    float4 wv = *(const float4*)&Ws[k * 128 + c0];
#pragma unroll
    for (int r = 0; r < 4; r++) {
      float a = AsT[(row0 + r) * 132 + k];
      acc[r][0] += a * wv.x; acc[r][1] += a * wv.y; acc[r][2] += a * wv.z; acc[r][3] += a * wv.w;
    }
  }
  float4 as4 = *(const float4*)&asrc[c0];
  float4 ad4 = *(const float4*)&adst[c0];
#pragma unroll
  for (int r = 0; r < 4; r++) {
    *(float4*)&H2[(row0 + r) * 132 + c0] = make_float4(acc[r][0], acc[r][1], acc[r][2], acc[r][3]);
    float ss = acc[r][0] * as4.x + acc[r][1] * as4.y + acc[r][2] * as4.z + acc[r][3] * as4.w;
    float sd = acc[r][0] * ad4.x + acc[r][1] * ad4.y + acc[r][2] * ad4.z + acc[r][3] * ad4.w;
#pragma unroll
    for (int m = 16; m > 0; m >>= 1) { ss += __shfl_xor(ss, m); sd += __shfl_xor(sd, m); }
    if (tx == 0) { ss_s[row0 + r] = ss; sd_s[row0 + r] = sd; }
  }
  __syncthreads();

  int row = tid >> 3, tc = tid & 7;
  int cb = tc * 16;
  int e0 = offs_s[row], e1 = offs_s[row + 1];
  float sdv = sd_s[row];
  float mx = -1e30f;
  for (int e = e0; e < e1; e++) {
    float t = ss_s[list_s[e]] + sdv;
    t = fmaxf(t, 0.2f * t);
    mx = fmaxf(mx, t);
  }
  float den = 0.f;
  float o[16];
#pragma unroll
  for (int j = 0; j < 16; j++) o[j] = 0.f;
  for (int e = e0; e < e1; e++) {
    int s = list_s[e];
    float t = ss_s[s] + sdv;
    t = fmaxf(t, 0.2f * t);
    float w = __expf(t - mx);
    den += w;
    const float* hp = &H2[s * 132 + cb];
    float4 h0 = *(const float4*)hp;
    float4 h1 = *(const float4*)(hp + 4);
    float4 h2v = *(const float4*)(hp + 8);
    float4 h3 = *(const float4*)(hp + 12);
    o[0] += w * h0.x;  o[1] += w * h0.y;  o[2] += w * h0.z;  o[3] += w * h0.w;
    o[4] += w * h1.x;  o[5] += w * h1.y;  o[6] += w * h1.z;  o[7] += w * h1.w;
    o[8] += w * h2v.x; o[9] += w * h2v.y; o[10] += w * h2v.z; o[11] += w * h2v.w;
    o[12] += w * h3.x; o[13] += w * h3.y; o[14] += w * h3.z; o[15] += w * h3.w;
  }
  float inv = 1.f / den;
  float xp = 0.f;
#pragma unroll
  for (int j = 0; j < 16; j++) xp += (o[j] * inv + gb[cb + j]) * fcw[cb + j];
#pragma unroll
  for (int m = 4; m > 0; m >>= 1) xp += __shfl_xor(xp, m);
  if (tc == 0) outp[b * 64 + row] = tanhf(xp + fcb[0]);
}

extern "C" void kernel_launch(void* const* d_in, const int* in_sizes, int n_in,
                              void* d_out, int out_size, void* d_ws, size_t ws_size,
                              hipStream_t stream) {
  (void)n_in; (void)out_size; (void)ws_size;
  const float* x        = (const float*)d_in[0];
  const float* gl_embed = (const float*)d_in[7];
  const float* gcn_w    = (const float*)d_in[8];
  const float* gcn_b    = (const float*)d_in[9];
  const float* mlp_w1   = (const float*)d_in[10];
  const float* mlp_b1   = (const float*)d_in[11];
  const float* mlp_w2   = (const float*)d_in[12];
  const float* mlp_b2   = (const float*)d_in[13];
  const float* ta_w     = (const float*)d_in[14];
  const float* ta_b     = (const float*)d_in[15];
  const float* ta_a     = (const float*)d_in[16];
  const float* ta_bias  = (const float*)d_in[17];
  const float* gat_w    = (const float*)d_in[18];
  const float* gat_asrc = (const float*)d_in[19];
  const float* gat_adst = (const float*)d_in[20];
  const float* gat_b    = (const float*)d_in[21];
  const float* fc_w     = (const float*)d_in[22];
  const float* fc_b     = (const float*)d_in[23];
  const int*   gat_ei   = (const int*)d_in[24];
  const int*   gl_ei    = (const int*)d_in[25];

  int E_gat = in_sizes[24] / (2 * BB);  // 1280
  int E_gl  = in_sizes[25] / (2 * BB);  // 1638

  float* ws = (float*)d_ws;
  float* HA    = ws + 0;        // 524288
  float* XS    = ws + 524288;   // 524288
  float* LEFT  = ws + 1048576;  // 1048576
  float* RIGHT = ws + 2097152;  // 1048576
  float* HT    = ws + 3145728;  // 524288
  int*   IP    = (int*)(ws + 3670016);
  int* GATOFF  = IP;            // 72
  int* GATLIST = IP + 72;       // 2048

  float* out_rec = (float*)d_out;
  float* out_pre = (float*)d_out + 524288;

  k_gcn<<<256, 256, 0, stream>>>(x, gl_embed, gcn_w, gcn_b, gl_ei, E_gl, gat_ei, E_gat,
                                 HA, GATOFF, GATLIST);
  k_mlp<<<256, 256, 0, stream>>>(HA, mlp_w1, mlp_b1, mlp_w2, mlp_b2, x, XS, out_rec);
  k_lr<<<2048, 256, 0, stream>>>(XS, ta_w, ta_b, LEFT, RIGHT);
  k_attn<<<256, 512, 0, stream>>>(LEFT, RIGHT, ta_a, ta_bias, XS, HT);
  k_gat<<<64, 512, 0, stream>>>(HT, gat_w, gat_asrc, gat_adst, gat_b, fc_w, fc_b,
                                GATOFF, GATLIST, out_pre);
}